// Round 11
// baseline (103.803 us; speedup 1.0000x reference)
//
#include <hip/hip_runtime.h>
#include <math.h>

// Problem constants
#define LL 3600
#define NODES 6400

typedef __attribute__((ext_vector_type(8))) _Float16 half8;
typedef __attribute__((ext_vector_type(4))) float f32x4;
typedef __attribute__((ext_vector_type(4))) unsigned short ushort4v;

// ---------------- fp16 helpers ----------------
__device__ __forceinline__ unsigned short f2h(float f) {
    union { _Float16 h; unsigned short u; } cv;
    cv.h = (_Float16)f;
    return cv.u;
}
__device__ __forceinline__ float h2f(unsigned short u) {
    union { unsigned short u; _Float16 h; } cv;
    cv.u = u;
    return (float)cv.h;
}

#define GLOAD16(gp, lp) __builtin_amdgcn_global_load_lds( \
    (const __attribute__((address_space(1))) unsigned int*)(const void*)(gp), \
    (__attribute__((address_space(3))) unsigned int*)(void*)(lp), 16, 0, 0)

// ================= MEGA PREP KERNEL =================
// blocks [0,2304): W1T | [2304,2944): W2T | [2944,4480): W3T
// [4480]: AeS | [4481,4581): adj | [4581,6181): tcn0 | [6181,6256): out bias-init
__global__ __launch_bounds__(256) void prep_kernel(
    const float* __restrict__ wg1, const float* __restrict__ wf1, const float* __restrict__ ws1,
    const float* __restrict__ sWv, const float* __restrict__ dWv,
    const float* __restrict__ sWq, const float* __restrict__ saq,
    const float* __restrict__ sWk, const float* __restrict__ sak,
    const float* __restrict__ dWq, const float* __restrict__ daq,
    const float* __restrict__ dWk, const float* __restrict__ dak,
    const float* __restrict__ fW1, const float* __restrict__ fW2, const float* __restrict__ fW3,
    const float* __restrict__ sWe, const float* __restrict__ sae,
    const float* __restrict__ E1, const float* __restrict__ E2,
    const float* __restrict__ x,
    const float* __restrict__ wg0, const float* __restrict__ bg0,
    const float* __restrict__ wf0, const float* __restrict__ bf0,
    const float* __restrict__ ws0, const float* __restrict__ bs0,
    const float* __restrict__ lg0, const float* __restrict__ lb0,
    const float* __restrict__ bo,
    unsigned short* __restrict__ W1h,
    unsigned short* __restrict__ W2h,
    unsigned short* __restrict__ W3h,
    float* __restrict__ AeS,
    int* __restrict__ cnt, int* __restrict__ idxs, float* __restrict__ logv,
    unsigned short* __restrict__ Xh,
    float* __restrict__ out) {
    int bid = blockIdx.x;
    int tid = threadIdx.x;

    if (bid < 2304) {
        int idx = bid * 256 + tid;
        int n = idx / 768, k = idx % 768;
        int which = n >> 8, o = n & 255;
        int tt = k >> 8, i = k & 255;
        const float* w = which == 0 ? wg1 : (which == 1 ? wf1 : ws1);
        W1h[idx] = f2h(w[(o * 256 + i) * 3 + tt]);
    } else if (bid < 2944) {
        int idx = (bid - 2304) * 256 + tid;
        int n = idx / 256, k = idx % 256;
        float v = 0.f;
        if (n < 256) v = sWv[k * 256 + n];
        else if (n < 512) v = dWv[k * 256 + (n - 256)];
        else if (n < 544) {
            int j = n - 512, g = j >> 3, h = j & 7;
            const float* Wm = g == 0 ? sWq : (g == 1 ? sWk : (g == 2 ? dWq : dWk));
            const float* am = g == 0 ? saq : (g == 1 ? sak : (g == 2 ? daq : dak));
            float s = 0.f;
            for (int d = 0; d < 32; d++) s += Wm[k * 256 + h * 32 + d] * am[h * 32 + d];
            v = s;
        }
        W2h[idx] = f2h(v);
    } else if (bid < 4480) {
        int idx = (bid - 2944) * 256 + tid;
        int n = idx / 512, k = idx % 512;
        float v = 0.f;
        if (k < 256) {
            if (n < 256) v = fW1[k * 256 + n];
            else if (n < 512) v = fW2[k * 256 + (n - 256)];
        } else {
            int c = k - 256;
            if (n < 256) v = fW1[c * 256 + n];
            else if (n >= 512) v = fW3[c * 256 + (n - 512)];
        }
        W3h[idx] = f2h(v);
    } else if (bid == 4480) {
        if (tid < 16) {
            int cc = tid / 8, h = tid % 8;
            float s = 0.f;
            for (int d = 0; d < 32; d++) s += sWe[cc * 256 + h * 32 + d] * sae[h * 32 + d];
            AeS[tid] = s;
        }
    } else if (bid < 4581) {
        // ---- adjacency: one wave per row
        int n = ((bid - 4481) * 256 + tid) >> 6;
        int lane = tid & 63;
        if (n >= 400) return;
        float e1[10];
        #pragma unroll
        for (int k = 0; k < 10; k++) e1[k] = E1[n * 10 + k];
        float p[7];
        #pragma unroll
        for (int i = 0; i < 7; i++) {
            int j = i * 64 + lane;
            if (j < 400) {
                float s = 0.f;
                #pragma unroll
                for (int k = 0; k < 10; k++) s += e1[k] * E2[j * 10 + k];
                p[i] = fmaxf(s, 0.f);
            } else p[i] = -1e30f;
        }
        float mx = -1e30f;
        #pragma unroll
        for (int i = 0; i < 7; i++) mx = fmaxf(mx, p[i]);
        #pragma unroll
        for (int o = 32; o > 0; o >>= 1) mx = fmaxf(mx, __shfl_xor(mx, o, 64));
        float sum = 0.f;
        #pragma unroll
        for (int i = 0; i < 7; i++) {
            int j = i * 64 + lane;
            if (j < 400) { p[i] = expf(p[i] - mx); sum += p[i]; }
        }
        #pragma unroll
        for (int o = 32; o > 0; o >>= 1) sum += __shfl_xor(sum, o, 64);
        float inv = 1.f / sum;
        float m[7];
        #pragma unroll
        for (int i = 0; i < 7; i++) {
            int j = i * 64 + lane;
            if (j < 400) { p[i] *= inv; m[i] = p[i]; }
            else m[i] = -1e30f;
        }
        for (int it = 0; it < 15; ++it) {
            float lm = m[0];
            #pragma unroll
            for (int i = 1; i < 7; i++) lm = fmaxf(lm, m[i]);
            float gm = lm;
            #pragma unroll
            for (int o = 32; o > 0; o >>= 1) gm = fmaxf(gm, __shfl_xor(gm, o, 64));
            unsigned long long msk = __ballot(lm == gm);
            int first = (int)(__ffsll((long long)msk)) - 1;
            if (lane == first) {
                #pragma unroll
                for (int i = 0; i < 7; i++) {
                    if (m[i] == gm) { m[i] = -1e30f; break; }
                }
            }
        }
        float kth = m[0];
        #pragma unroll
        for (int i = 1; i < 7; i++) kth = fmaxf(kth, m[i]);
        #pragma unroll
        for (int o = 32; o > 0; o >>= 1) kth = fmaxf(kth, __shfl_xor(kth, o, 64));
        int base = 0;
        #pragma unroll
        for (int i = 0; i < 7; i++) {
            int j = i * 64 + lane;
            bool pred = (j < 400) && (p[i] >= kth);
            unsigned long long msk = __ballot(pred);
            int pre = __popcll(msk & ((lane == 63) ? 0x7fffffffffffffffull : ((1ull << lane) - 1)));
            if (pred) {
                int pos = base + pre;
                if (pos < 64) {
                    idxs[n * 64 + pos] = j;
                    logv[n * 64 + pos] = logf(fmaxf(p[i], 1e-12f));
                }
            }
            base += __popcll(msk);
        }
        if (lane == 0) cnt[n] = base < 64 ? base : 64;
    } else if (bid < 6181) {
        // ---- TCN layer 0: one WAVE per node, 4 channels per lane, no barriers
        int lane = tid & 63;
        int node = (bid - 4581) * 4 + (tid >> 6);
        float xs[14];
        #pragma unroll
        for (int t = 0; t < 7; t++) {
            xs[t * 2]     = x[(size_t)(node * 12 + 5 + t) * 2];
            xs[t * 2 + 1] = x[(size_t)(node * 12 + 5 + t) * 2 + 1];
        }
        float wg[4][6], wf[4][6], wsv[4][6], bgv[4], bfv[4], bsv[4], gln[4], bln[4];
        #pragma unroll
        for (int cc = 0; cc < 4; cc++) {
            int o = lane * 4 + cc;
            #pragma unroll
            for (int i = 0; i < 6; i++) {
                wg[cc][i] = wg0[o * 6 + i];
                wf[cc][i] = wf0[o * 6 + i];
                wsv[cc][i] = ws0[o * 6 + i];
            }
            bgv[cc] = bg0[o]; bfv[cc] = bf0[o]; bsv[cc] = bs0[o];
            gln[cc] = lg0[o]; bln[cc] = lb0[o];
        }
        #pragma unroll
        for (int tt = 0; tt < 3; tt++) {
            int tb = 2 * tt;
            float y[4];
            float s1 = 0.f, s2 = 0.f;
            #pragma unroll
            for (int cc = 0; cc < 4; cc++) {
                float g = bgv[cc], f = bfv[cc], s = bsv[cc];
                #pragma unroll
                for (int k = 0; k < 3; k++) {
                    #pragma unroll
                    for (int c = 0; c < 2; c++) {
                        float xv = xs[(tb + k) * 2 + c];
                        g += wg[cc][c * 3 + k] * xv;
                        f += wf[cc][c * 3 + k] * xv;
                        s += wsv[cc][c * 3 + k] * xv;
                    }
                }
                float gate = 1.f / (1.f + expf(-g));
                y[cc] = gate * f + (1.f - gate) * s;
                s1 += y[cc];
                s2 += y[cc] * y[cc];
            }
            #pragma unroll
            for (int o = 32; o > 0; o >>= 1) {
                s1 += __shfl_xor(s1, o, 64);
                s2 += __shfl_xor(s2, o, 64);
            }
            float mean = s1 * (1.f / 256.f);
            float var = s2 * (1.f / 256.f) - mean * mean;
            float rstd = rsqrtf(var + 1e-5f);
            unsigned short h4[4];
            #pragma unroll
            for (int cc = 0; cc < 4; cc++) {
                float v = (y[cc] - mean) * rstd * gln[cc] + bln[cc];
                h4[cc] = f2h(fmaxf(v, 0.f));
            }
            unsigned long long pack = (unsigned long long)h4[0] | ((unsigned long long)h4[1] << 16)
                                    | ((unsigned long long)h4[2] << 32) | ((unsigned long long)h4[3] << 48);
            *(unsigned long long*)&Xh[(size_t)node * 768 + tt * 256 + lane * 4] = pack;
        }
    } else {
        int idx = (bid - 6181) * 256 + tid;
        if (idx < NODES * 3) out[idx] = bo[idx % 3];
    }
}

// ---------------- fp16 MFMA GEMM, 64x64 tile, BK=32, 3-stage counted-vmcnt pipeline ----------------
template<int K, int LDC, int GX>
__global__ __launch_bounds__(256, 6) void gemm_f16(
    const unsigned short* __restrict__ A,
    const unsigned short* __restrict__ BT,
    unsigned short* __restrict__ C) {
    __shared__ __align__(16) unsigned short lA[3][64 * 32];
    __shared__ __align__(16) unsigned short lB[3][64 * 32];
    int tid = threadIdx.x;
    int lane = tid & 63;
    int w = tid >> 6;
    int wm = w >> 1, wn = w & 1;
    int r = lane & 15, g4 = lane >> 4;

    constexpr int NWG = GX * 100;
    constexpr int Q = NWG / 8, R = NWG % 8;
    int flat = blockIdx.y * GX + blockIdx.x;
    int xcd = flat & 7, idx = flat >> 3;
    int nf = (xcd < R ? xcd * (Q + 1) : R * (Q + 1) + (xcd - R) * Q) + idx;
    int col0 = (nf % GX) * 64;
    int row0 = (nf / GX) * 64;

    f32x4 acc[2][2] = {};

    int rS = tid >> 2;
    int slot = tid & 3;
    int tk = (slot ^ (rS & 3)) * 8;

#define STAGE(sel, kk) do { \
    GLOAD16(A + (size_t)(row0 + rS) * K + (kk) + tk, &lA[sel][tid * 8]); \
    GLOAD16(BT + (size_t)(col0 + rS) * K + (kk) + tk, &lB[sel][tid * 8]); \
} while (0)

    int sw = (g4 ^ (r & 3)) << 3;

#define COMPUTE(cur) do { \
    half8 a_[2], b_[2]; \
    _Pragma("unroll") \
    for (int mi = 0; mi < 2; ++mi) \
        a_[mi] = *(const half8*)&lA[cur][(wm * 32 + mi * 16 + r) * 32 + sw]; \
    _Pragma("unroll") \
    for (int ni = 0; ni < 2; ++ni) \
        b_[ni] = *(const half8*)&lB[cur][(wn * 32 + ni * 16 + r) * 32 + sw]; \
    _Pragma("unroll") \
    for (int mi = 0; mi < 2; ++mi) \
        _Pragma("unroll") \
        for (int ni = 0; ni < 2; ++ni) \
            acc[mi][ni] = __builtin_amdgcn_mfma_f32_16x16x32_f16(a_[mi], b_[ni], acc[mi][ni], 0, 0, 0); \
} while (0)

    constexpr int NT = K >> 5;
    STAGE(0, 0);
    STAGE(1, 32);
    for (int t = 0; t < NT - 1; ++t) {
        asm volatile("s_waitcnt vmcnt(2)" ::: "memory");
        __builtin_amdgcn_s_barrier();
        if (t + 2 < NT) STAGE((t + 2) % 3, (t + 2) * 32);
        COMPUTE(t % 3);
    }
    asm volatile("s_waitcnt vmcnt(0)" ::: "memory");
    __builtin_amdgcn_s_barrier();
    COMPUTE((NT - 1) % 3);
#undef STAGE
#undef COMPUTE

    #pragma unroll
    for (int mi = 0; mi < 2; ++mi) {
        #pragma unroll
        for (int ni = 0; ni < 2; ++ni) {
            int rowb = row0 + wm * 32 + mi * 16 + g4 * 4;
            int colb = col0 + wn * 32 + ni * 16 + r;
            #pragma unroll
            for (int j = 0; j < 4; ++j)
                C[(size_t)(rowb + j) * LDC + colb] = f2h(acc[mi][ni][j]);
        }
    }
}

// ---------------- G3 with fused tail: U @ W3 -> fused -> @Wo -> atomic out ----------------
// Block: 32 rows x (64 cols x 3 chunks). Grid (4, 200) = 800 blocks. K=512, BK=32.
// Staging: waves 0-1 issue 3 B-loads/stage; waves 2-3 issue 3 B + 1 A = 4 -> per-wave vmcnt.
__global__ __launch_bounds__(256, 3) void gemm3_fused(
    const unsigned short* __restrict__ A,      // Uh (6400 x 512)
    const unsigned short* __restrict__ BT,     // W3h (768 x 512)
    const float* __restrict__ fb1, const float* __restrict__ fb2, const float* __restrict__ fb3,
    const float* __restrict__ Wo,
    float* __restrict__ out) {
    __shared__ __align__(16) unsigned short lA[3][32 * 32];       // 6KB
    __shared__ __align__(16) unsigned short lB[3][3][64 * 32];    // 36KB -> 42KB
    int tid = threadIdx.x;
    int lane = tid & 63;
    int w = tid >> 6;
    int wm = w >> 1, wn = w & 1;
    int r = lane & 15, g4 = lane >> 4;

    // bijective XCD swizzle: NWG=800, R=0, Q=100
    int flat = blockIdx.y * 4 + blockIdx.x;
    int xcd = flat & 7, idx = flat >> 3;
    int nf = xcd * 100 + idx;
    int c0 = (nf % 4) * 64;            // channel-slice base in [0,256)
    int row0 = (nf / 4) * 32;

    f32x4 acc[3][2] = {};              // [chunk][ni]

    // B staging: 768 chunks, 3 per thread; A staging: 128 chunks, threads 128-255
    int aTid = tid - 128;
    int aRow = aTid >> 2, aSlot = aTid & 3;
    int aTk = (aSlot ^ (aRow & 3)) * 8;

#define STAGE3(sel, kk) do { \
    _Pragma("unroll") \
    for (int q = 0; q < 3; ++q) { \
        int cch = q * 256 + tid; \
        int brow = cch >> 2, bslot = cch & 3; \
        int q2 = brow >> 6, r2 = brow & 63; \
        int btk = (bslot ^ (r2 & 3)) * 8; \
        GLOAD16(BT + (size_t)(c0 + q2 * 256 + r2) * 512 + (kk) + btk, &lB[sel][0][cch * 8]); \
    } \
    if (tid >= 128) \
        GLOAD16(A + (size_t)(row0 + aRow) * 512 + (kk) + aTk, &lA[sel][aTid * 8]); \
} while (0)

    int sw = (g4 ^ (r & 3)) << 3;

#define COMPUTE3(cur) do { \
    half8 a_, b_[3][2]; \
    a_ = *(const half8*)&lA[cur][(wm * 16 + r) * 32 + sw]; \
    _Pragma("unroll") \
    for (int q = 0; q < 3; ++q) \
        _Pragma("unroll") \
        for (int ni = 0; ni < 2; ++ni) \
            b_[q][ni] = *(const half8*)&lB[cur][q][(wn * 32 + ni * 16 + r) * 32 + sw]; \
    _Pragma("unroll") \
    for (int q = 0; q < 3; ++q) \
        _Pragma("unroll") \
        for (int ni = 0; ni < 2; ++ni) \
            acc[q][ni] = __builtin_amdgcn_mfma_f32_16x16x32_f16(a_, b_[q][ni], acc[q][ni], 0, 0, 0); \
} while (0)

    constexpr int NT = 16;  // 512/32
    STAGE3(0, 0);
    STAGE3(1, 32);
    for (int t = 0; t < NT - 1; ++t) {
        if (w < 2) { asm volatile("s_waitcnt vmcnt(3)" ::: "memory"); }
        else       { asm volatile("s_waitcnt vmcnt(4)" ::: "memory"); }
        __builtin_amdgcn_s_barrier();
        if (t + 2 < NT) STAGE3((t + 2) % 3, (t + 2) * 32);
        COMPUTE3(t % 3);
    }
    asm volatile("s_waitcnt vmcnt(0)" ::: "memory");
    __builtin_amdgcn_s_barrier();
    COMPUTE3((NT - 1) % 3);
#undef STAGE3
#undef COMPUTE3

    // fused tail
    float v0[4] = {}, v1[4] = {}, v2[4] = {};
    #pragma unroll
    for (int ni = 0; ni < 2; ++ni) {
        int ch = c0 + wn * 32 + ni * 16 + r;
        float b1 = fb1[ch], b2 = fb2[ch], b3 = fb3[ch];
        float w0 = Wo[ch * 3 + 0], w1 = Wo[ch * 3 + 1], w2 = Wo[ch * 3 + 2];
        #pragma unroll
        for (int j = 0; j < 4; ++j) {
            float g = 1.f / (1.f + expf(-(acc[0][ni][j] + b1)));
            float a2 = acc[1][ni][j] + b2;
            float a3 = acc[2][ni][j] + b3;
            float fused = tanhf(g * a2 + (1.f - g) * a3);
            v0[j] += fused * w0;
            v1[j] += fused * w1;
            v2[j] += fused * w2;
        }
    }
    #pragma unroll
    for (int off = 1; off < 16; off <<= 1) {
        #pragma unroll
        for (int j = 0; j < 4; ++j) {
            v0[j] += __shfl_xor(v0[j], off, 64);
            v1[j] += __shfl_xor(v1[j], off, 64);
            v2[j] += __shfl_xor(v2[j], off, 64);
        }
    }
    if (r == 0) {
        int rowb = row0 + wm * 16 + g4 * 4;
        #pragma unroll
        for (int j = 0; j < 4; ++j) {
            atomicAdd(&out[(size_t)(rowb + j) * 3 + 0], v0[j]);
            atomicAdd(&out[(size_t)(rowb + j) * 3 + 1], v1[j]);
            atomicAdd(&out[(size_t)(rowb + j) * 3 + 2], v2[j]);
        }
    }
}

// ---------------- layer-1 epilogue: one WAVE per node, no barriers ----------------
__global__ __launch_bounds__(256) void epi1_kernel(
    const unsigned short* __restrict__ Y1, const float* __restrict__ x,
    const float* __restrict__ bg1, const float* __restrict__ bf1, const float* __restrict__ bs1,
    const float* __restrict__ lg, const float* __restrict__ lb,
    const float* __restrict__ wsk, const float* __restrict__ bsk,
    unsigned short* __restrict__ HLh) {
    int lane = threadIdx.x & 63;
    int node = blockIdx.x * 4 + (threadIdx.x >> 6);
    size_t base = (size_t)node * 768;
    ushort4v yg = *(const ushort4v*)&Y1[base + lane * 4];
    ushort4v yf = *(const ushort4v*)&Y1[base + 256 + lane * 4];
    ushort4v ys = *(const ushort4v*)&Y1[base + 512 + lane * 4];
    float y[4];
    float s1 = 0.f, s2 = 0.f;
    #pragma unroll
    for (int cc = 0; cc < 4; cc++) {
        int o = lane * 4 + cc;
        float g = h2f(yg[cc]) + bg1[o];
        float f = h2f(yf[cc]) + bf1[o];
        float s = h2f(ys[cc]) + bs1[o];
        float gate = 1.f / (1.f + expf(-g));
        y[cc] = gate * f + (1.f - gate) * s;
        s1 += y[cc];
        s2 += y[cc] * y[cc];
    }
    #pragma unroll
    for (int off = 32; off > 0; off >>= 1) {
        s1 += __shfl_xor(s1, off, 64);
        s2 += __shfl_xor(s2, off, 64);
    }
    float mean = s1 * (1.f / 256.f);
    float var = s2 * (1.f / 256.f) - mean * mean;
    float rstd = rsqrtf(var + 1e-5f);
    float x0 = x[(size_t)(node * 12 + 11) * 2];
    float x1 = x[(size_t)(node * 12 + 11) * 2 + 1];
    unsigned short h4[4];
    #pragma unroll
    for (int cc = 0; cc < 4; cc++) {
        int o = lane * 4 + cc;
        float v = (y[cc] - mean) * rstd * lg[o] + lb[o];
        v = fmaxf(v, 0.f);
        float res = x0 * wsk[o] + x1 * wsk[256 + o] + bsk[o];
        h4[cc] = f2h(v + res);
    }
    unsigned long long pack = (unsigned long long)h4[0] | ((unsigned long long)h4[1] << 16)
                            | ((unsigned long long)h4[2] << 32) | ((unsigned long long)h4[3] << 48);
    *(unsigned long long*)&HLh[(size_t)node * 256 + lane * 4] = pack;
}

// ---------------- fused GAT: one block per node, 1 barrier, short2 gathers ----------------
__global__ __launch_bounds__(256) void gat_kernel(
    const unsigned short* __restrict__ Y2, const float* __restrict__ ef,
    const int* __restrict__ fei, const float* __restrict__ AeS,
    const int* __restrict__ cnt, const int* __restrict__ idxs, const float* __restrict__ logv,
    unsigned short* __restrict__ Uh) {
    int node = blockIdx.x;
    int b = node / 400, n = node % 400;
    int tid = threadIdx.x;
    __shared__ int snd[9];
    __shared__ float alf[9][8];
    __shared__ float invdf[8];
    __shared__ int jidx[64];
    __shared__ float sca[64][8];
    __shared__ float alb[64][8];
    __shared__ float invda[8];
    __shared__ float svf[9][8];
    int c = cnt[n];

    if (tid < 64) {
        int lane = tid;
        if (lane < 9) snd[lane] = fei[LL + n * 9 + lane];
        for (int e = lane; e < 72; e += 64) {
            int j = e >> 3, h = e & 7;
            int l = n * 9 + j;
            float e0 = ef[((size_t)b * LL + l) * 2];
            float e1 = ef[((size_t)b * LL + l) * 2 + 1];
            float ae = e0 * AeS[h] + e1 * AeS[8 + h];
            float aq = h2f(Y2[(size_t)node * 640 + 512 + h]);
            float ak = h2f(Y2[((size_t)(b * 400 + snd[j])) * 640 + 520 + h]);
            float s = aq + ak + ae;
            svf[j][h] = s > 0.f ? s : 0.2f * s;
        }
        if (lane < 8) {
            int h = lane;
            float mx = -1e30f;
            #pragma unroll
            for (int j = 0; j < 9; j++) mx = fmaxf(mx, svf[j][h]);
            float den = 0.f;
            #pragma unroll
            for (int j = 0; j < 9; j++) { float e = expf(svf[j][h] - mx); alf[j][h] = e; den += e; }
            invdf[h] = 1.f / fmaxf(den, 1e-12f);
        }
    } else if (tid < 128) {
        int lane = tid - 64;
        if (lane < c) jidx[lane] = idxs[n * 64 + lane];
        float jl = (lane < c) ? logv[n * 64 + lane] : 0.f;
        for (int e = lane; e < c * 8; e += 64) {
            int j = e >> 3, h = e & 7;
            float aq = h2f(Y2[(size_t)node * 640 + 528 + h]);
            float ak = h2f(Y2[((size_t)(b * 400 + jidx[j])) * 640 + 536 + h]);
            float s = aq + ak;
            s = s > 0.f ? s : 0.2f * s;
            sca[j][h] = s + __shfl(jl, j, 64);
        }
        int h = lane >> 3, grp = lane & 7;
        float mx = -1e30f;
        for (int j = grp; j < c; j += 8) mx = fmaxf(mx, sca[j][h]);
        #pragma unroll
        for (int o = 1; o < 8; o <<= 1) mx = fmaxf(mx, __shfl_xor(mx, o, 64));
        float s = 0.f;
        for (int j = grp; j < c; j += 8) { float e = expf(sca[j][h] - mx); alb[j][h] = e; s += e; }
        #pragma unroll
        for (int o = 1; o < 8; o <<= 1) s += __shfl_xor(s, o, 64);
        if (grp == 0) invda[h] = 1.f / s;
    }
    __syncthreads();

    if (tid < 128) {
        int ch = tid * 2;
        int h = ch >> 5;
        float a0 = 0.f, a1 = 0.f;
        #pragma unroll
        for (int j = 0; j < 9; j++) {
            unsigned v = *(const unsigned*)&Y2[((size_t)(b * 400 + snd[j])) * 640 + ch];
            float al = alf[j][h];
            a0 += al * h2f((unsigned short)(v & 0xffff));
            a1 += al * h2f((unsigned short)(v >> 16));
        }
        float iv = invdf[h];
        a0 *= iv; a1 *= iv;
        a0 = a0 > 0.f ? a0 : (expf(a0) - 1.f);
        a1 = a1 > 0.f ? a1 : (expf(a1) - 1.f);
        unsigned o = (unsigned)f2h(a0) | ((unsigned)f2h(a1) << 16);
        *(unsigned*)&Uh[(size_t)node * 512 + ch] = o;
    } else {
        int ch = (tid - 128) * 2;
        int h = ch >> 5;
        float a0 = 0.f, a1 = 0.f;
        for (int j = 0; j < c; j++) {
            unsigned v = *(const unsigned*)&Y2[((size_t)(b * 400 + jidx[j])) * 640 + 256 + ch];
            float al = alb[j][h];
            a0 += al * h2f((unsigned short)(v & 0xffff));
            a1 += al * h2f((unsigned short)(v >> 16));
        }
        float iv = invda[h];
        a0 *= iv; a1 *= iv;
        a0 = a0 > 0.f ? a0 : (expf(a0) - 1.f);
        a1 = a1 > 0.f ? a1 : (expf(a1) - 1.f);
        unsigned o = (unsigned)f2h(a0) | ((unsigned)f2h(a1) << 16);
        *(unsigned*)&Uh[(size_t)node * 512 + 256 + ch] = o;
    }
}

// ---------------- launcher ----------------
extern "C" void kernel_launch(void* const* d_in, const int* in_sizes, int n_in,
                              void* d_out, int out_size, void* d_ws, size_t ws_size,
                              hipStream_t stream) {
    const float* x   = (const float*)d_in[0];
    const float* ef  = (const float*)d_in[1];
    const int*   fei = (const int*)d_in[2];
    const float* wg0 = (const float*)d_in[3];
    const float* bg0 = (const float*)d_in[4];
    const float* wf0 = (const float*)d_in[5];
    const float* bf0 = (const float*)d_in[6];
    const float* ws0 = (const float*)d_in[7];
    const float* bs0 = (const float*)d_in[8];
    const float* ln0g = (const float*)d_in[9];
    const float* ln0b = (const float*)d_in[10];
    const float* wg1 = (const float*)d_in[11];
    const float* bg1 = (const float*)d_in[12];
    const float* wf1 = (const float*)d_in[13];
    const float* bf1 = (const float*)d_in[14];
    const float* ws1 = (const float*)d_in[15];
    const float* bs1 = (const float*)d_in[16];
    const float* ln1g = (const float*)d_in[17];
    const float* ln1b = (const float*)d_in[18];
    const float* wsk = (const float*)d_in[19];
    const float* bsk = (const float*)d_in[20];
    const float* sWq = (const float*)d_in[21];
    const float* sWk = (const float*)d_in[22];
    const float* sWv = (const float*)d_in[23];
    const float* sWe = (const float*)d_in[24];
    const float* saq = (const float*)d_in[25];
    const float* sak = (const float*)d_in[26];
    const float* sae = (const float*)d_in[27];
    const float* dWq = (const float*)d_in[28];
    const float* dWk = (const float*)d_in[29];
    const float* dWv = (const float*)d_in[30];
    const float* daq = (const float*)d_in[31];
    const float* dak = (const float*)d_in[32];
    const float* E1  = (const float*)d_in[33];
    const float* E2  = (const float*)d_in[34];
    const float* fW1 = (const float*)d_in[35];
    const float* fb1 = (const float*)d_in[36];
    const float* fW2 = (const float*)d_in[37];
    const float* fb2 = (const float*)d_in[38];
    const float* fW3 = (const float*)d_in[39];
    const float* fb3 = (const float*)d_in[40];
    const float* Wo  = (const float*)d_in[41];
    const float* bo  = (const float*)d_in[42];
    float* out = (float*)d_out;

    char* b = (char*)d_ws;
    unsigned short* Xh  = (unsigned short*)(b + 0);          // 9,830,400
    unsigned short* Yh  = (unsigned short*)(b + 9830400);    // 9,830,400 (Y1/Y2 fp16, reused)
    unsigned short* HLh = (unsigned short*)(b + 19660800);   // 3,276,800
    unsigned short* Uh  = (unsigned short*)(b + 22937600);   // 6,553,600
    unsigned short* W1h = (unsigned short*)(b + 29491200);   // 1,179,648
    unsigned short* W2h = (unsigned short*)(b + 30670848);   // 327,680
    unsigned short* W3h = (unsigned short*)(b + 30998528);   // 786,432
    float*          AES = (float*)(b + 31784960);            // 64 (+pad)
    float*          LOGV= (float*)(b + 31785216);            // 102,400
    int*            CNT = (int*)(b + 31887616);              // 1,600
    int*            IDX = (int*)(b + 31889216);              // 102,400

    prep_kernel<<<6256, 256, 0, stream>>>(
        wg1, wf1, ws1,
        sWv, dWv, sWq, saq, sWk, sak, dWq, daq, dWk, dak,
        fW1, fW2, fW3, sWe, sae, E1, E2,
        x, wg0, bg0, wf0, bf0, ws0, bs0, ln0g, ln0b, bo,
        W1h, W2h, W3h, AES,
        CNT, IDX, LOGV, Xh, out);

    // G1: Y1 = X @ W1  (M=6400, N=768, K=768) -> fp16
    gemm_f16<768, 768, 12><<<dim3(12, 100), 256, 0, stream>>>(Xh, W1h, Yh);

    // epi1: one wave per node
    epi1_kernel<<<1600, 256, 0, stream>>>(Yh, x, bg1, bf1, bs1, ln1g, ln1b, wsk, bsk, HLh);

    // G2: Y2 = HL @ W2 (M=6400, N=576 used, K=256) -> fp16
    gemm_f16<256, 640, 9><<<dim3(9, 100), 256, 0, stream>>>(HLh, W2h, Yh);

    // fused attention stages -> U (one block per node)
    gat_kernel<<<NODES, 256, 0, stream>>>(Yh, ef, fei, AES, CNT, IDX, LOGV, Uh);

    // G3 + fused tail: out += tanh-fuse(U @ W3) @ Wo   (out pre-init'd with bo)
    gemm3_fused<<<dim3(4, 200), 256, 0, stream>>>(Uh, W3h, fb1, fb2, fb3, Wo, out);
}

// Round 12
// 97.055 us; speedup vs baseline: 1.0695x; 1.0695x over previous
//
#include <hip/hip_runtime.h>
#include <math.h>

// Problem constants
#define LL 3600
#define NODES 6400

typedef __attribute__((ext_vector_type(8))) _Float16 half8;
typedef __attribute__((ext_vector_type(4))) float f32x4;
typedef __attribute__((ext_vector_type(4))) unsigned short ushort4v;

// ---------------- fp16 helpers ----------------
__device__ __forceinline__ unsigned short f2h(float f) {
    union { _Float16 h; unsigned short u; } cv;
    cv.h = (_Float16)f;
    return cv.u;
}
__device__ __forceinline__ float h2f(unsigned short u) {
    union { unsigned short u; _Float16 h; } cv;
    cv.u = u;
    return (float)cv.h;
}

#define GLOAD16(gp, lp) __builtin_amdgcn_global_load_lds( \
    (const __attribute__((address_space(1))) unsigned int*)(const void*)(gp), \
    (__attribute__((address_space(3))) unsigned int*)(void*)(lp), 16, 0, 0)

// ================= MEGA PREP KERNEL =================
// blocks [0,2304): W1T | [2304,2944): W2T | [2944,4480): W3T
// [4480]: AeS | [4481,4581): adj | [4581,6181): tcn0 | [6181,6256): out bias-init
__global__ __launch_bounds__(256) void prep_kernel(
    const float* __restrict__ wg1, const float* __restrict__ wf1, const float* __restrict__ ws1,
    const float* __restrict__ sWv, const float* __restrict__ dWv,
    const float* __restrict__ sWq, const float* __restrict__ saq,
    const float* __restrict__ sWk, const float* __restrict__ sak,
    const float* __restrict__ dWq, const float* __restrict__ daq,
    const float* __restrict__ dWk, const float* __restrict__ dak,
    const float* __restrict__ fW1, const float* __restrict__ fW2, const float* __restrict__ fW3,
    const float* __restrict__ sWe, const float* __restrict__ sae,
    const float* __restrict__ E1, const float* __restrict__ E2,
    const float* __restrict__ x,
    const float* __restrict__ wg0, const float* __restrict__ bg0,
    const float* __restrict__ wf0, const float* __restrict__ bf0,
    const float* __restrict__ ws0, const float* __restrict__ bs0,
    const float* __restrict__ lg0, const float* __restrict__ lb0,
    const float* __restrict__ bo,
    unsigned short* __restrict__ W1h,
    unsigned short* __restrict__ W2h,
    unsigned short* __restrict__ W3h,
    float* __restrict__ AeS,
    int* __restrict__ cnt, int* __restrict__ idxs, float* __restrict__ logv,
    unsigned short* __restrict__ Xh,
    float* __restrict__ out) {
    int bid = blockIdx.x;
    int tid = threadIdx.x;

    if (bid < 2304) {
        int idx = bid * 256 + tid;
        int n = idx / 768, k = idx % 768;
        int which = n >> 8, o = n & 255;
        int tt = k >> 8, i = k & 255;
        const float* w = which == 0 ? wg1 : (which == 1 ? wf1 : ws1);
        W1h[idx] = f2h(w[(o * 256 + i) * 3 + tt]);
    } else if (bid < 2944) {
        int idx = (bid - 2304) * 256 + tid;
        int n = idx / 256, k = idx % 256;
        float v = 0.f;
        if (n < 256) v = sWv[k * 256 + n];
        else if (n < 512) v = dWv[k * 256 + (n - 256)];
        else if (n < 544) {
            int j = n - 512, g = j >> 3, h = j & 7;
            const float* Wm = g == 0 ? sWq : (g == 1 ? sWk : (g == 2 ? dWq : dWk));
            const float* am = g == 0 ? saq : (g == 1 ? sak : (g == 2 ? daq : dak));
            float s = 0.f;
            for (int d = 0; d < 32; d++) s += Wm[k * 256 + h * 32 + d] * am[h * 32 + d];
            v = s;
        }
        W2h[idx] = f2h(v);
    } else if (bid < 4480) {
        int idx = (bid - 2944) * 256 + tid;
        int n = idx / 512, k = idx % 512;
        float v = 0.f;
        if (k < 256) {
            if (n < 256) v = fW1[k * 256 + n];
            else if (n < 512) v = fW2[k * 256 + (n - 256)];
        } else {
            int c = k - 256;
            if (n < 256) v = fW1[c * 256 + n];
            else if (n >= 512) v = fW3[c * 256 + (n - 512)];
        }
        W3h[idx] = f2h(v);
    } else if (bid == 4480) {
        if (tid < 16) {
            int cc = tid / 8, h = tid % 8;
            float s = 0.f;
            for (int d = 0; d < 32; d++) s += sWe[cc * 256 + h * 32 + d] * sae[h * 32 + d];
            AeS[tid] = s;
        }
    } else if (bid < 4581) {
        // ---- adjacency: one wave per row
        int n = ((bid - 4481) * 256 + tid) >> 6;
        int lane = tid & 63;
        if (n >= 400) return;
        float e1[10];
        #pragma unroll
        for (int k = 0; k < 10; k++) e1[k] = E1[n * 10 + k];
        float p[7];
        #pragma unroll
        for (int i = 0; i < 7; i++) {
            int j = i * 64 + lane;
            if (j < 400) {
                float s = 0.f;
                #pragma unroll
                for (int k = 0; k < 10; k++) s += e1[k] * E2[j * 10 + k];
                p[i] = fmaxf(s, 0.f);
            } else p[i] = -1e30f;
        }
        float mx = -1e30f;
        #pragma unroll
        for (int i = 0; i < 7; i++) mx = fmaxf(mx, p[i]);
        #pragma unroll
        for (int o = 32; o > 0; o >>= 1) mx = fmaxf(mx, __shfl_xor(mx, o, 64));
        float sum = 0.f;
        #pragma unroll
        for (int i = 0; i < 7; i++) {
            int j = i * 64 + lane;
            if (j < 400) { p[i] = expf(p[i] - mx); sum += p[i]; }
        }
        #pragma unroll
        for (int o = 32; o > 0; o >>= 1) sum += __shfl_xor(sum, o, 64);
        float inv = 1.f / sum;
        float m[7];
        #pragma unroll
        for (int i = 0; i < 7; i++) {
            int j = i * 64 + lane;
            if (j < 400) { p[i] *= inv; m[i] = p[i]; }
            else m[i] = -1e30f;
        }
        for (int it = 0; it < 15; ++it) {
            float lm = m[0];
            #pragma unroll
            for (int i = 1; i < 7; i++) lm = fmaxf(lm, m[i]);
            float gm = lm;
            #pragma unroll
            for (int o = 32; o > 0; o >>= 1) gm = fmaxf(gm, __shfl_xor(gm, o, 64));
            unsigned long long msk = __ballot(lm == gm);
            int first = (int)(__ffsll((long long)msk)) - 1;
            if (lane == first) {
                #pragma unroll
                for (int i = 0; i < 7; i++) {
                    if (m[i] == gm) { m[i] = -1e30f; break; }
                }
            }
        }
        float kth = m[0];
        #pragma unroll
        for (int i = 1; i < 7; i++) kth = fmaxf(kth, m[i]);
        #pragma unroll
        for (int o = 32; o > 0; o >>= 1) kth = fmaxf(kth, __shfl_xor(kth, o, 64));
        int base = 0;
        #pragma unroll
        for (int i = 0; i < 7; i++) {
            int j = i * 64 + lane;
            bool pred = (j < 400) && (p[i] >= kth);
            unsigned long long msk = __ballot(pred);
            int pre = __popcll(msk & ((lane == 63) ? 0x7fffffffffffffffull : ((1ull << lane) - 1)));
            if (pred) {
                int pos = base + pre;
                if (pos < 64) {
                    idxs[n * 64 + pos] = j;
                    logv[n * 64 + pos] = logf(fmaxf(p[i], 1e-12f));
                }
            }
            base += __popcll(msk);
        }
        if (lane == 0) cnt[n] = base < 64 ? base : 64;
    } else if (bid < 6181) {
        // ---- TCN layer 0: one WAVE per node, 4 channels per lane, no barriers
        int lane = tid & 63;
        int node = (bid - 4581) * 4 + (tid >> 6);
        float xs[14];
        #pragma unroll
        for (int t = 0; t < 7; t++) {
            xs[t * 2]     = x[(size_t)(node * 12 + 5 + t) * 2];
            xs[t * 2 + 1] = x[(size_t)(node * 12 + 5 + t) * 2 + 1];
        }
        float wg[4][6], wf[4][6], wsv[4][6], bgv[4], bfv[4], bsv[4], gln[4], bln[4];
        #pragma unroll
        for (int cc = 0; cc < 4; cc++) {
            int o = lane * 4 + cc;
            #pragma unroll
            for (int i = 0; i < 6; i++) {
                wg[cc][i] = wg0[o * 6 + i];
                wf[cc][i] = wf0[o * 6 + i];
                wsv[cc][i] = ws0[o * 6 + i];
            }
            bgv[cc] = bg0[o]; bfv[cc] = bf0[o]; bsv[cc] = bs0[o];
            gln[cc] = lg0[o]; bln[cc] = lb0[o];
        }
        #pragma unroll
        for (int tt = 0; tt < 3; tt++) {
            int tb = 2 * tt;
            float y[4];
            float s1 = 0.f, s2 = 0.f;
            #pragma unroll
            for (int cc = 0; cc < 4; cc++) {
                float g = bgv[cc], f = bfv[cc], s = bsv[cc];
                #pragma unroll
                for (int k = 0; k < 3; k++) {
                    #pragma unroll
                    for (int c = 0; c < 2; c++) {
                        float xv = xs[(tb + k) * 2 + c];
                        g += wg[cc][c * 3 + k] * xv;
                        f += wf[cc][c * 3 + k] * xv;
                        s += wsv[cc][c * 3 + k] * xv;
                    }
                }
                float gate = 1.f / (1.f + expf(-g));
                y[cc] = gate * f + (1.f - gate) * s;
                s1 += y[cc];
                s2 += y[cc] * y[cc];
            }
            #pragma unroll
            for (int o = 32; o > 0; o >>= 1) {
                s1 += __shfl_xor(s1, o, 64);
                s2 += __shfl_xor(s2, o, 64);
            }
            float mean = s1 * (1.f / 256.f);
            float var = s2 * (1.f / 256.f) - mean * mean;
            float rstd = rsqrtf(var + 1e-5f);
            unsigned short h4[4];
            #pragma unroll
            for (int cc = 0; cc < 4; cc++) {
                float v = (y[cc] - mean) * rstd * gln[cc] + bln[cc];
                h4[cc] = f2h(fmaxf(v, 0.f));
            }
            unsigned long long pack = (unsigned long long)h4[0] | ((unsigned long long)h4[1] << 16)
                                    | ((unsigned long long)h4[2] << 32) | ((unsigned long long)h4[3] << 48);
            *(unsigned long long*)&Xh[(size_t)node * 768 + tt * 256 + lane * 4] = pack;
        }
    } else {
        int idx = (bid - 6181) * 256 + tid;
        if (idx < NODES * 3) out[idx] = bo[idx % 3];
    }
}

// ---------------- fp16 MFMA GEMM, 64x64 tile, BK=32, 3-stage counted-vmcnt ----------------
template<int K, int LDC, int GX>
__global__ __launch_bounds__(256, 6) void gemm_f16(
    const unsigned short* __restrict__ A,
    const unsigned short* __restrict__ BT,
    unsigned short* __restrict__ C) {
    __shared__ __align__(16) unsigned short lA[3][64 * 32];
    __shared__ __align__(16) unsigned short lB[3][64 * 32];
    int tid = threadIdx.x;
    int lane = tid & 63;
    int w = tid >> 6;
    int wm = w >> 1, wn = w & 1;
    int r = lane & 15, g4 = lane >> 4;

    constexpr int NWG = GX * 100;
    constexpr int Q = NWG / 8, R = NWG % 8;
    int flat = blockIdx.y * GX + blockIdx.x;
    int xcd = flat & 7, idx = flat >> 3;
    int nf = (xcd < R ? xcd * (Q + 1) : R * (Q + 1) + (xcd - R) * Q) + idx;
    int col0 = (nf % GX) * 64;
    int row0 = (nf / GX) * 64;

    f32x4 acc[2][2] = {};

    int rS = tid >> 2;
    int slot = tid & 3;
    int tk = (slot ^ (rS & 3)) * 8;

#define STAGE(sel, kk) do { \
    GLOAD16(A + (size_t)(row0 + rS) * K + (kk) + tk, &lA[sel][tid * 8]); \
    GLOAD16(BT + (size_t)(col0 + rS) * K + (kk) + tk, &lB[sel][tid * 8]); \
} while (0)

    int sw = (g4 ^ (r & 3)) << 3;

#define COMPUTE(cur) do { \
    half8 a_[2], b_[2]; \
    _Pragma("unroll") \
    for (int mi = 0; mi < 2; ++mi) \
        a_[mi] = *(const half8*)&lA[cur][(wm * 32 + mi * 16 + r) * 32 + sw]; \
    _Pragma("unroll") \
    for (int ni = 0; ni < 2; ++ni) \
        b_[ni] = *(const half8*)&lB[cur][(wn * 32 + ni * 16 + r) * 32 + sw]; \
    _Pragma("unroll") \
    for (int mi = 0; mi < 2; ++mi) \
        _Pragma("unroll") \
        for (int ni = 0; ni < 2; ++ni) \
            acc[mi][ni] = __builtin_amdgcn_mfma_f32_16x16x32_f16(a_[mi], b_[ni], acc[mi][ni], 0, 0, 0); \
} while (0)

    constexpr int NT = K >> 5;
    STAGE(0, 0);
    STAGE(1, 32);
    for (int t = 0; t < NT - 1; ++t) {
        asm volatile("s_waitcnt vmcnt(2)" ::: "memory");
        __builtin_amdgcn_s_barrier();
        if (t + 2 < NT) STAGE((t + 2) % 3, (t + 2) * 32);
        COMPUTE(t % 3);
    }
    asm volatile("s_waitcnt vmcnt(0)" ::: "memory");
    __builtin_amdgcn_s_barrier();
    COMPUTE((NT - 1) % 3);
#undef STAGE
#undef COMPUTE

    #pragma unroll
    for (int mi = 0; mi < 2; ++mi) {
        #pragma unroll
        for (int ni = 0; ni < 2; ++ni) {
            int rowb = row0 + wm * 32 + mi * 16 + g4 * 4;
            int colb = col0 + wn * 32 + ni * 16 + r;
            #pragma unroll
            for (int j = 0; j < 4; ++j)
                C[(size_t)(rowb + j) * LDC + colb] = f2h(acc[mi][ni][j]);
        }
    }
}

// ---------------- fp16 MFMA GEMM, 128x64 tile, BK=32, 3-stage counted-vmcnt ----------------
// 4 waves as 2x2; each wave 64 rows x 32 cols (4x2 frags, 8 MFMA/step).
template<int K, int LDC, int GX, int GY>
__global__ __launch_bounds__(256, 4) void gemm_f16_big(
    const unsigned short* __restrict__ A,
    const unsigned short* __restrict__ BT,
    unsigned short* __restrict__ C) {
    __shared__ __align__(16) unsigned short lA[3][128 * 32];   // 24KB
    __shared__ __align__(16) unsigned short lB[3][64 * 32];    // 12KB -> 36KB
    int tid = threadIdx.x;
    int lane = tid & 63;
    int w = tid >> 6;
    int wm = w >> 1, wn = w & 1;
    int r = lane & 15, g4 = lane >> 4;

    constexpr int NWG = GX * GY;
    constexpr int Q = NWG / 8, R = NWG % 8;
    int flat = blockIdx.y * GX + blockIdx.x;
    int xcd = flat & 7, idx = flat >> 3;
    int nf = (xcd < R ? xcd * (Q + 1) : R * (Q + 1) + (xcd - R) * Q) + idx;
    int col0 = (nf % GX) * 64;
    int row0 = (nf / GX) * 128;

    f32x4 acc[4][2] = {};

    int rS = tid >> 2;                  // 0..63
    int slot = tid & 3;
    int tkA0 = (slot ^ (rS & 3)) * 8;               // A rows 0..63
    int tkA1 = (slot ^ ((rS + 64) & 3)) * 8;        // A rows 64..127 (same as tkA0: +64 keeps &3)
    int tkB = tkA0;

#define STAGE(sel, kk) do { \
    GLOAD16(A + (size_t)(row0 + rS) * K + (kk) + tkA0, &lA[sel][tid * 8]); \
    GLOAD16(A + (size_t)(row0 + 64 + rS) * K + (kk) + tkA1, &lA[sel][(tid + 256) * 8]); \
    GLOAD16(BT + (size_t)(col0 + rS) * K + (kk) + tkB, &lB[sel][tid * 8]); \
} while (0)

    int sw = (g4 ^ (r & 3)) << 3;

#define COMPUTE(cur) do { \
    half8 a_[4], b_[2]; \
    _Pragma("unroll") \
    for (int mi = 0; mi < 4; ++mi) \
        a_[mi] = *(const half8*)&lA[cur][(wm * 64 + mi * 16 + r) * 32 + sw]; \
    _Pragma("unroll") \
    for (int ni = 0; ni < 2; ++ni) \
        b_[ni] = *(const half8*)&lB[cur][(wn * 32 + ni * 16 + r) * 32 + sw]; \
    _Pragma("unroll") \
    for (int mi = 0; mi < 4; ++mi) \
        _Pragma("unroll") \
        for (int ni = 0; ni < 2; ++ni) \
            acc[mi][ni] = __builtin_amdgcn_mfma_f32_16x16x32_f16(a_[mi], b_[ni], acc[mi][ni], 0, 0, 0); \
} while (0)

    constexpr int NT = K >> 5;
    STAGE(0, 0);
    STAGE(1, 32);
    for (int t = 0; t < NT - 1; ++t) {
        asm volatile("s_waitcnt vmcnt(3)" ::: "memory");
        __builtin_amdgcn_s_barrier();
        if (t + 2 < NT) STAGE((t + 2) % 3, (t + 2) * 32);
        COMPUTE(t % 3);
    }
    asm volatile("s_waitcnt vmcnt(0)" ::: "memory");
    __builtin_amdgcn_s_barrier();
    COMPUTE((NT - 1) % 3);
#undef STAGE
#undef COMPUTE

    #pragma unroll
    for (int mi = 0; mi < 4; ++mi) {
        #pragma unroll
        for (int ni = 0; ni < 2; ++ni) {
            int rowb = row0 + wm * 64 + mi * 16 + g4 * 4;
            int colb = col0 + wn * 32 + ni * 16 + r;
            #pragma unroll
            for (int j = 0; j < 4; ++j)
                C[(size_t)(rowb + j) * LDC + colb] = f2h(acc[mi][ni][j]);
        }
    }
}

// ---------------- G3 with fused tail (R10 version): 64 rows x 3x64 cols, grid (4,100) ----------------
__global__ __launch_bounds__(256, 3) void gemm3_fused(
    const unsigned short* __restrict__ A,      // Uh (6400 x 512)
    const unsigned short* __restrict__ BT,     // W3h (768 x 512)
    const float* __restrict__ fb1, const float* __restrict__ fb2, const float* __restrict__ fb3,
    const float* __restrict__ Wo,
    float* __restrict__ out) {
    __shared__ __align__(16) unsigned short lA[3][64 * 32];       // 12KB
    __shared__ __align__(16) unsigned short lB[3][3][64 * 32];    // 36KB -> 48KB
    int tid = threadIdx.x;
    int lane = tid & 63;
    int w = tid >> 6;
    int wm = w >> 1, wn = w & 1;
    int r = lane & 15, g4 = lane >> 4;

    // bijective XCD swizzle: NWG=400, R=0
    constexpr int NWG = 400;
    constexpr int Q = NWG / 8;
    int flat = blockIdx.y * 4 + blockIdx.x;
    int xcd = flat & 7, idx = flat >> 3;
    int nf = xcd * Q + idx;
    int c0 = (nf % 4) * 64;
    int row0 = (nf / 4) * 64;

    f32x4 acc[3][2][2] = {};

    int rS = tid >> 2;
    int slot = tid & 3;
    int tk = (slot ^ (rS & 3)) * 8;

#define STAGE3(sel, kk) do { \
    GLOAD16(A + (size_t)(row0 + rS) * 512 + (kk) + tk, &lA[sel][tid * 8]); \
    GLOAD16(BT + (size_t)(c0 + rS) * 512 + (kk) + tk, &lB[sel][0][tid * 8]); \
    GLOAD16(BT + (size_t)(c0 + 256 + rS) * 512 + (kk) + tk, &lB[sel][1][tid * 8]); \
    GLOAD16(BT + (size_t)(c0 + 512 + rS) * 512 + (kk) + tk, &lB[sel][2][tid * 8]); \
} while (0)

    int sw = (g4 ^ (r & 3)) << 3;

#define COMPUTE3(cur) do { \
    half8 a_[2], b_[3][2]; \
    _Pragma("unroll") \
    for (int mi = 0; mi < 2; ++mi) \
        a_[mi] = *(const half8*)&lA[cur][(wm * 32 + mi * 16 + r) * 32 + sw]; \
    _Pragma("unroll") \
    for (int q = 0; q < 3; ++q) \
        _Pragma("unroll") \
        for (int ni = 0; ni < 2; ++ni) \
            b_[q][ni] = *(const half8*)&lB[cur][q][(wn * 32 + ni * 16 + r) * 32 + sw]; \
    _Pragma("unroll") \
    for (int q = 0; q < 3; ++q) \
        _Pragma("unroll") \
        for (int mi = 0; mi < 2; ++mi) \
            _Pragma("unroll") \
            for (int ni = 0; ni < 2; ++ni) \
                acc[q][mi][ni] = __builtin_amdgcn_mfma_f32_16x16x32_f16(a_[mi], b_[q][ni], acc[q][mi][ni], 0, 0, 0); \
} while (0)

    constexpr int NT = 16;  // 512/32
    STAGE3(0, 0);
    STAGE3(1, 32);
    for (int t = 0; t < NT - 1; ++t) {
        asm volatile("s_waitcnt vmcnt(4)" ::: "memory");
        __builtin_amdgcn_s_barrier();
        if (t + 2 < NT) STAGE3((t + 2) % 3, (t + 2) * 32);
        COMPUTE3(t % 3);
    }
    asm volatile("s_waitcnt vmcnt(0)" ::: "memory");
    __builtin_amdgcn_s_barrier();
    COMPUTE3((NT - 1) % 3);
#undef STAGE3
#undef COMPUTE3

    #pragma unroll
    for (int mi = 0; mi < 2; ++mi) {
        float v0[4] = {}, v1[4] = {}, v2[4] = {};
        #pragma unroll
        for (int ni = 0; ni < 2; ++ni) {
            int ch = c0 + wn * 32 + ni * 16 + r;
            float b1 = fb1[ch], b2 = fb2[ch], b3 = fb3[ch];
            float w0 = Wo[ch * 3 + 0], w1 = Wo[ch * 3 + 1], w2 = Wo[ch * 3 + 2];
            #pragma unroll
            for (int j = 0; j < 4; ++j) {
                float g = 1.f / (1.f + expf(-(acc[0][mi][ni][j] + b1)));
                float a2 = acc[1][mi][ni][j] + b2;
                float a3 = acc[2][mi][ni][j] + b3;
                float fused = tanhf(g * a2 + (1.f - g) * a3);
                v0[j] += fused * w0;
                v1[j] += fused * w1;
                v2[j] += fused * w2;
            }
        }
        #pragma unroll
        for (int off = 1; off < 16; off <<= 1) {
            #pragma unroll
            for (int j = 0; j < 4; ++j) {
                v0[j] += __shfl_xor(v0[j], off, 64);
                v1[j] += __shfl_xor(v1[j], off, 64);
                v2[j] += __shfl_xor(v2[j], off, 64);
            }
        }
        if (r == 0) {
            int rowb = row0 + wm * 32 + mi * 16 + g4 * 4;
            #pragma unroll
            for (int j = 0; j < 4; ++j) {
                atomicAdd(&out[(size_t)(rowb + j) * 3 + 0], v0[j]);
                atomicAdd(&out[(size_t)(rowb + j) * 3 + 1], v1[j]);
                atomicAdd(&out[(size_t)(rowb + j) * 3 + 2], v2[j]);
            }
        }
    }
}

// ---------------- layer-1 epilogue: one WAVE per node, no barriers ----------------
__global__ __launch_bounds__(256) void epi1_kernel(
    const unsigned short* __restrict__ Y1, const float* __restrict__ x,
    const float* __restrict__ bg1, const float* __restrict__ bf1, const float* __restrict__ bs1,
    const float* __restrict__ lg, const float* __restrict__ lb,
    const float* __restrict__ wsk, const float* __restrict__ bsk,
    unsigned short* __restrict__ HLh) {
    int lane = threadIdx.x & 63;
    int node = blockIdx.x * 4 + (threadIdx.x >> 6);
    size_t base = (size_t)node * 768;
    ushort4v yg = *(const ushort4v*)&Y1[base + lane * 4];
    ushort4v yf = *(const ushort4v*)&Y1[base + 256 + lane * 4];
    ushort4v ys = *(const ushort4v*)&Y1[base + 512 + lane * 4];
    float y[4];
    float s1 = 0.f, s2 = 0.f;
    #pragma unroll
    for (int cc = 0; cc < 4; cc++) {
        int o = lane * 4 + cc;
        float g = h2f(yg[cc]) + bg1[o];
        float f = h2f(yf[cc]) + bf1[o];
        float s = h2f(ys[cc]) + bs1[o];
        float gate = 1.f / (1.f + expf(-g));
        y[cc] = gate * f + (1.f - gate) * s;
        s1 += y[cc];
        s2 += y[cc] * y[cc];
    }
    #pragma unroll
    for (int off = 32; off > 0; off >>= 1) {
        s1 += __shfl_xor(s1, off, 64);
        s2 += __shfl_xor(s2, off, 64);
    }
    float mean = s1 * (1.f / 256.f);
    float var = s2 * (1.f / 256.f) - mean * mean;
    float rstd = rsqrtf(var + 1e-5f);
    float x0 = x[(size_t)(node * 12 + 11) * 2];
    float x1 = x[(size_t)(node * 12 + 11) * 2 + 1];
    unsigned short h4[4];
    #pragma unroll
    for (int cc = 0; cc < 4; cc++) {
        int o = lane * 4 + cc;
        float v = (y[cc] - mean) * rstd * lg[o] + lb[o];
        v = fmaxf(v, 0.f);
        float res = x0 * wsk[o] + x1 * wsk[256 + o] + bsk[o];
        h4[cc] = f2h(v + res);
    }
    unsigned long long pack = (unsigned long long)h4[0] | ((unsigned long long)h4[1] << 16)
                            | ((unsigned long long)h4[2] << 32) | ((unsigned long long)h4[3] << 48);
    *(unsigned long long*)&HLh[(size_t)node * 256 + lane * 4] = pack;
}

// ---------------- fused GAT: one block per node, 1 barrier, short2 gathers ----------------
__global__ __launch_bounds__(256) void gat_kernel(
    const unsigned short* __restrict__ Y2, const float* __restrict__ ef,
    const int* __restrict__ fei, const float* __restrict__ AeS,
    const int* __restrict__ cnt, const int* __restrict__ idxs, const float* __restrict__ logv,
    unsigned short* __restrict__ Uh) {
    int node = blockIdx.x;
    int b = node / 400, n = node % 400;
    int tid = threadIdx.x;
    __shared__ int snd[9];
    __shared__ float alf[9][8];
    __shared__ float invdf[8];
    __shared__ int jidx[64];
    __shared__ float sca[64][8];
    __shared__ float alb[64][8];
    __shared__ float invda[8];
    __shared__ float svf[9][8];
    int c = cnt[n];

    if (tid < 64) {
        int lane = tid;
        if (lane < 9) snd[lane] = fei[LL + n * 9 + lane];
        for (int e = lane; e < 72; e += 64) {
            int j = e >> 3, h = e & 7;
            int l = n * 9 + j;
            float e0 = ef[((size_t)b * LL + l) * 2];
            float e1 = ef[((size_t)b * LL + l) * 2 + 1];
            float ae = e0 * AeS[h] + e1 * AeS[8 + h];
            float aq = h2f(Y2[(size_t)node * 640 + 512 + h]);
            float ak = h2f(Y2[((size_t)(b * 400 + snd[j])) * 640 + 520 + h]);
            float s = aq + ak + ae;
            svf[j][h] = s > 0.f ? s : 0.2f * s;
        }
        if (lane < 8) {
            int h = lane;
            float mx = -1e30f;
            #pragma unroll
            for (int j = 0; j < 9; j++) mx = fmaxf(mx, svf[j][h]);
            float den = 0.f;
            #pragma unroll
            for (int j = 0; j < 9; j++) { float e = expf(svf[j][h] - mx); alf[j][h] = e; den += e; }
            invdf[h] = 1.f / fmaxf(den, 1e-12f);
        }
    } else if (tid < 128) {
        int lane = tid - 64;
        if (lane < c) jidx[lane] = idxs[n * 64 + lane];
        float jl = (lane < c) ? logv[n * 64 + lane] : 0.f;
        for (int e = lane; e < c * 8; e += 64) {
            int j = e >> 3, h = e & 7;
            float aq = h2f(Y2[(size_t)node * 640 + 528 + h]);
            float ak = h2f(Y2[((size_t)(b * 400 + jidx[j])) * 640 + 536 + h]);
            float s = aq + ak;
            s = s > 0.f ? s : 0.2f * s;
            sca[j][h] = s + __shfl(jl, j, 64);
        }
        int h = lane >> 3, grp = lane & 7;
        float mx = -1e30f;
        for (int j = grp; j < c; j += 8) mx = fmaxf(mx, sca[j][h]);
        #pragma unroll
        for (int o = 1; o < 8; o <<= 1) mx = fmaxf(mx, __shfl_xor(mx, o, 64));
        float s = 0.f;
        for (int j = grp; j < c; j += 8) { float e = expf(sca[j][h] - mx); alb[j][h] = e; s += e; }
        #pragma unroll
        for (int o = 1; o < 8; o <<= 1) s += __shfl_xor(s, o, 64);
        if (grp == 0) invda[h] = 1.f / s;
    }
    __syncthreads();

    if (tid < 128) {
        int ch = tid * 2;
        int h = ch >> 5;
        float a0 = 0.f, a1 = 0.f;
        #pragma unroll
        for (int j = 0; j < 9; j++) {
            unsigned v = *(const unsigned*)&Y2[((size_t)(b * 400 + snd[j])) * 640 + ch];
            float al = alf[j][h];
            a0 += al * h2f((unsigned short)(v & 0xffff));
            a1 += al * h2f((unsigned short)(v >> 16));
        }
        float iv = invdf[h];
        a0 *= iv; a1 *= iv;
        a0 = a0 > 0.f ? a0 : (expf(a0) - 1.f);
        a1 = a1 > 0.f ? a1 : (expf(a1) - 1.f);
        unsigned o = (unsigned)f2h(a0) | ((unsigned)f2h(a1) << 16);
        *(unsigned*)&Uh[(size_t)node * 512 + ch] = o;
    } else {
        int ch = (tid - 128) * 2;
        int h = ch >> 5;
        float a0 = 0.f, a1 = 0.f;
        for (int j = 0; j < c; j++) {
            unsigned v = *(const unsigned*)&Y2[((size_t)(b * 400 + jidx[j])) * 640 + 256 + ch];
            float al = alb[j][h];
            a0 += al * h2f((unsigned short)(v & 0xffff));
            a1 += al * h2f((unsigned short)(v >> 16));
        }
        float iv = invda[h];
        a0 *= iv; a1 *= iv;
        a0 = a0 > 0.f ? a0 : (expf(a0) - 1.f);
        a1 = a1 > 0.f ? a1 : (expf(a1) - 1.f);
        unsigned o = (unsigned)f2h(a0) | ((unsigned)f2h(a1) << 16);
        *(unsigned*)&Uh[(size_t)node * 512 + 256 + ch] = o;
    }
}

// ---------------- launcher ----------------
extern "C" void kernel_launch(void* const* d_in, const int* in_sizes, int n_in,
                              void* d_out, int out_size, void* d_ws, size_t ws_size,
                              hipStream_t stream) {
    const float* x   = (const float*)d_in[0];
    const float* ef  = (const float*)d_in[1];
    const int*   fei = (const int*)d_in[2];
    const float* wg0 = (const float*)d_in[3];
    const float* bg0 = (const float*)d_in[4];
    const float* wf0 = (const float*)d_in[5];
    const float* bf0 = (const float*)d_in[6];
    const float* ws0 = (const float*)d_in[7];
    const float* bs0 = (const float*)d_in[8];
    const float* ln0g = (const float*)d_in[9];
    const float* ln0b = (const float*)d_in[10];
    const float* wg1 = (const float*)d_in[11];
    const float* bg1 = (const float*)d_in[12];
    const float* wf1 = (const float*)d_in[13];
    const float* bf1 = (const float*)d_in[14];
    const float* ws1 = (const float*)d_in[15];
    const float* bs1 = (const float*)d_in[16];
    const float* ln1g = (const float*)d_in[17];
    const float* ln1b = (const float*)d_in[18];
    const float* wsk = (const float*)d_in[19];
    const float* bsk = (const float*)d_in[20];
    const float* sWq = (const float*)d_in[21];
    const float* sWk = (const float*)d_in[22];
    const float* sWv = (const float*)d_in[23];
    const float* sWe = (const float*)d_in[24];
    const float* saq = (const float*)d_in[25];
    const float* sak = (const float*)d_in[26];
    const float* sae = (const float*)d_in[27];
    const float* dWq = (const float*)d_in[28];
    const float* dWk = (const float*)d_in[29];
    const float* dWv = (const float*)d_in[30];
    const float* daq = (const float*)d_in[31];
    const float* dak = (const float*)d_in[32];
    const float* E1  = (const float*)d_in[33];
    const float* E2  = (const float*)d_in[34];
    const float* fW1 = (const float*)d_in[35];
    const float* fb1 = (const float*)d_in[36];
    const float* fW2 = (const float*)d_in[37];
    const float* fb2 = (const float*)d_in[38];
    const float* fW3 = (const float*)d_in[39];
    const float* fb3 = (const float*)d_in[40];
    const float* Wo  = (const float*)d_in[41];
    const float* bo  = (const float*)d_in[42];
    float* out = (float*)d_out;

    char* b = (char*)d_ws;
    unsigned short* Xh  = (unsigned short*)(b + 0);          // 9,830,400
    unsigned short* Yh  = (unsigned short*)(b + 9830400);    // 9,830,400 (Y1/Y2 fp16, reused)
    unsigned short* HLh = (unsigned short*)(b + 19660800);   // 3,276,800
    unsigned short* Uh  = (unsigned short*)(b + 22937600);   // 6,553,600
    unsigned short* W1h = (unsigned short*)(b + 29491200);   // 1,179,648
    unsigned short* W2h = (unsigned short*)(b + 30670848);   // 327,680
    unsigned short* W3h = (unsigned short*)(b + 30998528);   // 786,432
    float*          AES = (float*)(b + 31784960);            // 64 (+pad)
    float*          LOGV= (float*)(b + 31785216);            // 102,400
    int*            CNT = (int*)(b + 31887616);              // 1,600
    int*            IDX = (int*)(b + 31889216);              // 102,400

    prep_kernel<<<6256, 256, 0, stream>>>(
        wg1, wf1, ws1,
        sWv, dWv, sWq, saq, sWk, sak, dWq, daq, dWk, dak,
        fW1, fW2, fW3, sWe, sae, E1, E2,
        x, wg0, bg0, wf0, bf0, ws0, bs0, ln0g, ln0b, bo,
        W1h, W2h, W3h, AES,
        CNT, IDX, LOGV, Xh, out);

    // G1: Y1 = X @ W1  (M=6400, N=768, K=768) -> fp16, 128x64 tiles
    gemm_f16_big<768, 768, 12, 50><<<dim3(12, 50), 256, 0, stream>>>(Xh, W1h, Yh);

    // epi1: one wave per node
    epi1_kernel<<<1600, 256, 0, stream>>>(Yh, x, bg1, bf1, bs1, ln1g, ln1b, wsk, bsk, HLh);

    // G2: Y2 = HL @ W2 (M=6400, N=576 used, K=256) -> fp16, 64x64 tiles
    gemm_f16<256, 640, 9><<<dim3(9, 100), 256, 0, stream>>>(HLh, W2h, Yh);

    // fused attention stages -> U (one block per node)
    gat_kernel<<<NODES, 256, 0, stream>>>(Yh, ef, fei, AES, CNT, IDX, LOGV, Uh);

    // G3 + fused tail (R10 64-row version): out += tanh-fuse(U @ W3) @ Wo
    gemm3_fused<<<dim3(4, 100), 256, 0, stream>>>(Uh, W3h, fb1, fb2, fb3, Wo, out);
}

// Round 13
// 94.007 us; speedup vs baseline: 1.1042x; 1.0324x over previous
//
#include <hip/hip_runtime.h>
#include <math.h>

// Problem constants
#define LL 3600
#define NODES 6400

typedef __attribute__((ext_vector_type(8))) _Float16 half8;
typedef __attribute__((ext_vector_type(4))) float f32x4;
typedef __attribute__((ext_vector_type(4))) unsigned short ushort4v;

// ---------------- fp16 helpers ----------------
__device__ __forceinline__ unsigned short f2h(float f) {
    union { _Float16 h; unsigned short u; } cv;
    cv.h = (_Float16)f;
    return cv.u;
}
__device__ __forceinline__ float h2f(unsigned short u) {
    union { unsigned short u; _Float16 h; } cv;
    cv.u = u;
    return (float)cv.h;
}

#define GLOAD16(gp, lp) __builtin_amdgcn_global_load_lds( \
    (const __attribute__((address_space(1))) unsigned int*)(const void*)(gp), \
    (__attribute__((address_space(3))) unsigned int*)(void*)(lp), 16, 0, 0)

// ================= MEGA PREP KERNEL =================
// blocks [0,2304): W1T | [2304,2944): W2T | [2944,4480): W3T
// [4480]: AeS | [4481,4581): adj | [4581,6181): tcn0 | [6181,6256): out bias-init
__global__ __launch_bounds__(256) void prep_kernel(
    const float* __restrict__ wg1, const float* __restrict__ wf1, const float* __restrict__ ws1,
    const float* __restrict__ sWv, const float* __restrict__ dWv,
    const float* __restrict__ sWq, const float* __restrict__ saq,
    const float* __restrict__ sWk, const float* __restrict__ sak,
    const float* __restrict__ dWq, const float* __restrict__ daq,
    const float* __restrict__ dWk, const float* __restrict__ dak,
    const float* __restrict__ fW1, const float* __restrict__ fW2, const float* __restrict__ fW3,
    const float* __restrict__ sWe, const float* __restrict__ sae,
    const float* __restrict__ E1, const float* __restrict__ E2,
    const float* __restrict__ x,
    const float* __restrict__ wg0, const float* __restrict__ bg0,
    const float* __restrict__ wf0, const float* __restrict__ bf0,
    const float* __restrict__ ws0, const float* __restrict__ bs0,
    const float* __restrict__ lg0, const float* __restrict__ lb0,
    const float* __restrict__ bo,
    unsigned short* __restrict__ W1h,
    unsigned short* __restrict__ W2h,
    unsigned short* __restrict__ W3h,
    float* __restrict__ AeS,
    int* __restrict__ cnt, int* __restrict__ idxs, float* __restrict__ logv,
    unsigned short* __restrict__ Xh,
    float* __restrict__ out) {
    int bid = blockIdx.x;
    int tid = threadIdx.x;

    if (bid < 2304) {
        int idx = bid * 256 + tid;
        int n = idx / 768, k = idx % 768;
        int which = n >> 8, o = n & 255;
        int tt = k >> 8, i = k & 255;
        const float* w = which == 0 ? wg1 : (which == 1 ? wf1 : ws1);
        W1h[idx] = f2h(w[(o * 256 + i) * 3 + tt]);
    } else if (bid < 2944) {
        int idx = (bid - 2304) * 256 + tid;
        int n = idx / 256, k = idx % 256;
        float v = 0.f;
        if (n < 256) v = sWv[k * 256 + n];
        else if (n < 512) v = dWv[k * 256 + (n - 256)];
        else if (n < 544) {
            int j = n - 512, g = j >> 3, h = j & 7;
            const float* Wm = g == 0 ? sWq : (g == 1 ? sWk : (g == 2 ? dWq : dWk));
            const float* am = g == 0 ? saq : (g == 1 ? sak : (g == 2 ? daq : dak));
            float s = 0.f;
            for (int d = 0; d < 32; d++) s += Wm[k * 256 + h * 32 + d] * am[h * 32 + d];
            v = s;
        }
        W2h[idx] = f2h(v);
    } else if (bid < 4480) {
        int idx = (bid - 2944) * 256 + tid;
        int n = idx / 512, k = idx % 512;
        float v = 0.f;
        if (k < 256) {
            if (n < 256) v = fW1[k * 256 + n];
            else if (n < 512) v = fW2[k * 256 + (n - 256)];
        } else {
            int c = k - 256;
            if (n < 256) v = fW1[c * 256 + n];
            else if (n >= 512) v = fW3[c * 256 + (n - 512)];
        }
        W3h[idx] = f2h(v);
    } else if (bid == 4480) {
        if (tid < 16) {
            int cc = tid / 8, h = tid % 8;
            float s = 0.f;
            for (int d = 0; d < 32; d++) s += sWe[cc * 256 + h * 32 + d] * sae[h * 32 + d];
            AeS[tid] = s;
        }
    } else if (bid < 4581) {
        // ---- adjacency: one wave per row
        int n = ((bid - 4481) * 256 + tid) >> 6;
        int lane = tid & 63;
        if (n >= 400) return;
        float e1[10];
        #pragma unroll
        for (int k = 0; k < 10; k++) e1[k] = E1[n * 10 + k];
        float p[7];
        #pragma unroll
        for (int i = 0; i < 7; i++) {
            int j = i * 64 + lane;
            if (j < 400) {
                float s = 0.f;
                #pragma unroll
                for (int k = 0; k < 10; k++) s += e1[k] * E2[j * 10 + k];
                p[i] = fmaxf(s, 0.f);
            } else p[i] = -1e30f;
        }
        float mx = -1e30f;
        #pragma unroll
        for (int i = 0; i < 7; i++) mx = fmaxf(mx, p[i]);
        #pragma unroll
        for (int o = 32; o > 0; o >>= 1) mx = fmaxf(mx, __shfl_xor(mx, o, 64));
        float sum = 0.f;
        #pragma unroll
        for (int i = 0; i < 7; i++) {
            int j = i * 64 + lane;
            if (j < 400) { p[i] = expf(p[i] - mx); sum += p[i]; }
        }
        #pragma unroll
        for (int o = 32; o > 0; o >>= 1) sum += __shfl_xor(sum, o, 64);
        float inv = 1.f / sum;
        float m[7];
        #pragma unroll
        for (int i = 0; i < 7; i++) {
            int j = i * 64 + lane;
            if (j < 400) { p[i] *= inv; m[i] = p[i]; }
            else m[i] = -1e30f;
        }
        for (int it = 0; it < 15; ++it) {
            float lm = m[0];
            #pragma unroll
            for (int i = 1; i < 7; i++) lm = fmaxf(lm, m[i]);
            float gm = lm;
            #pragma unroll
            for (int o = 32; o > 0; o >>= 1) gm = fmaxf(gm, __shfl_xor(gm, o, 64));
            unsigned long long msk = __ballot(lm == gm);
            int first = (int)(__ffsll((long long)msk)) - 1;
            if (lane == first) {
                #pragma unroll
                for (int i = 0; i < 7; i++) {
                    if (m[i] == gm) { m[i] = -1e30f; break; }
                }
            }
        }
        float kth = m[0];
        #pragma unroll
        for (int i = 1; i < 7; i++) kth = fmaxf(kth, m[i]);
        #pragma unroll
        for (int o = 32; o > 0; o >>= 1) kth = fmaxf(kth, __shfl_xor(kth, o, 64));
        int base = 0;
        #pragma unroll
        for (int i = 0; i < 7; i++) {
            int j = i * 64 + lane;
            bool pred = (j < 400) && (p[i] >= kth);
            unsigned long long msk = __ballot(pred);
            int pre = __popcll(msk & ((lane == 63) ? 0x7fffffffffffffffull : ((1ull << lane) - 1)));
            if (pred) {
                int pos = base + pre;
                if (pos < 64) {
                    idxs[n * 64 + pos] = j;
                    logv[n * 64 + pos] = logf(fmaxf(p[i], 1e-12f));
                }
            }
            base += __popcll(msk);
        }
        if (lane == 0) cnt[n] = base < 64 ? base : 64;
    } else if (bid < 6181) {
        // ---- TCN layer 0: one WAVE per node, 4 channels per lane, no barriers
        int lane = tid & 63;
        int node = (bid - 4581) * 4 + (tid >> 6);
        float xs[14];
        #pragma unroll
        for (int t = 0; t < 7; t++) {
            xs[t * 2]     = x[(size_t)(node * 12 + 5 + t) * 2];
            xs[t * 2 + 1] = x[(size_t)(node * 12 + 5 + t) * 2 + 1];
        }
        float wg[4][6], wf[4][6], wsv[4][6], bgv[4], bfv[4], bsv[4], gln[4], bln[4];
        #pragma unroll
        for (int cc = 0; cc < 4; cc++) {
            int o = lane * 4 + cc;
            #pragma unroll
            for (int i = 0; i < 6; i++) {
                wg[cc][i] = wg0[o * 6 + i];
                wf[cc][i] = wf0[o * 6 + i];
                wsv[cc][i] = ws0[o * 6 + i];
            }
            bgv[cc] = bg0[o]; bfv[cc] = bf0[o]; bsv[cc] = bs0[o];
            gln[cc] = lg0[o]; bln[cc] = lb0[o];
        }
        #pragma unroll
        for (int tt = 0; tt < 3; tt++) {
            int tb = 2 * tt;
            float y[4];
            float s1 = 0.f, s2 = 0.f;
            #pragma unroll
            for (int cc = 0; cc < 4; cc++) {
                float g = bgv[cc], f = bfv[cc], s = bsv[cc];
                #pragma unroll
                for (int k = 0; k < 3; k++) {
                    #pragma unroll
                    for (int c = 0; c < 2; c++) {
                        float xv = xs[(tb + k) * 2 + c];
                        g += wg[cc][c * 3 + k] * xv;
                        f += wf[cc][c * 3 + k] * xv;
                        s += wsv[cc][c * 3 + k] * xv;
                    }
                }
                float gate = 1.f / (1.f + expf(-g));
                y[cc] = gate * f + (1.f - gate) * s;
                s1 += y[cc];
                s2 += y[cc] * y[cc];
            }
            #pragma unroll
            for (int o = 32; o > 0; o >>= 1) {
                s1 += __shfl_xor(s1, o, 64);
                s2 += __shfl_xor(s2, o, 64);
            }
            float mean = s1 * (1.f / 256.f);
            float var = s2 * (1.f / 256.f) - mean * mean;
            float rstd = rsqrtf(var + 1e-5f);
            unsigned short h4[4];
            #pragma unroll
            for (int cc = 0; cc < 4; cc++) {
                float v = (y[cc] - mean) * rstd * gln[cc] + bln[cc];
                h4[cc] = f2h(fmaxf(v, 0.f));
            }
            unsigned long long pack = (unsigned long long)h4[0] | ((unsigned long long)h4[1] << 16)
                                    | ((unsigned long long)h4[2] << 32) | ((unsigned long long)h4[3] << 48);
            *(unsigned long long*)&Xh[(size_t)node * 768 + tt * 256 + lane * 4] = pack;
        }
    } else {
        int idx = (bid - 6181) * 256 + tid;
        if (idx < NODES * 3) out[idx] = bo[idx % 3];
    }
}

// ---------------- fp16 MFMA GEMM, 128x64 tile, BK=32, 3-stage counted-vmcnt ----------------
// 4 waves as 2x2; each wave 64 rows x 32 cols (4x2 frags, 8 MFMA/step).
template<int K, int LDC, int GX, int GY>
__global__ __launch_bounds__(256, 4) void gemm_f16_big(
    const unsigned short* __restrict__ A,
    const unsigned short* __restrict__ BT,
    unsigned short* __restrict__ C) {
    __shared__ __align__(16) unsigned short lA[3][128 * 32];   // 24KB
    __shared__ __align__(16) unsigned short lB[3][64 * 32];    // 12KB -> 36KB
    int tid = threadIdx.x;
    int lane = tid & 63;
    int w = tid >> 6;
    int wm = w >> 1, wn = w & 1;
    int r = lane & 15, g4 = lane >> 4;

    constexpr int NWG = GX * GY;
    constexpr int Q = NWG / 8, R = NWG % 8;
    int flat = blockIdx.y * GX + blockIdx.x;
    int xcd = flat & 7, idx = flat >> 3;
    int nf = (xcd < R ? xcd * (Q + 1) : R * (Q + 1) + (xcd - R) * Q) + idx;
    int col0 = (nf % GX) * 64;
    int row0 = (nf / GX) * 128;

    f32x4 acc[4][2] = {};

    int rS = tid >> 2;
    int slot = tid & 3;
    int tkA0 = (slot ^ (rS & 3)) * 8;
    int tkA1 = (slot ^ ((rS + 64) & 3)) * 8;
    int tkB = tkA0;

#define STAGE(sel, kk) do { \
    GLOAD16(A + (size_t)(row0 + rS) * K + (kk) + tkA0, &lA[sel][tid * 8]); \
    GLOAD16(A + (size_t)(row0 + 64 + rS) * K + (kk) + tkA1, &lA[sel][(tid + 256) * 8]); \
    GLOAD16(BT + (size_t)(col0 + rS) * K + (kk) + tkB, &lB[sel][tid * 8]); \
} while (0)

    int sw = (g4 ^ (r & 3)) << 3;

#define COMPUTE(cur) do { \
    half8 a_[4], b_[2]; \
    _Pragma("unroll") \
    for (int mi = 0; mi < 4; ++mi) \
        a_[mi] = *(const half8*)&lA[cur][(wm * 64 + mi * 16 + r) * 32 + sw]; \
    _Pragma("unroll") \
    for (int ni = 0; ni < 2; ++ni) \
        b_[ni] = *(const half8*)&lB[cur][(wn * 32 + ni * 16 + r) * 32 + sw]; \
    _Pragma("unroll") \
    for (int mi = 0; mi < 4; ++mi) \
        _Pragma("unroll") \
        for (int ni = 0; ni < 2; ++ni) \
            acc[mi][ni] = __builtin_amdgcn_mfma_f32_16x16x32_f16(a_[mi], b_[ni], acc[mi][ni], 0, 0, 0); \
} while (0)

    constexpr int NT = K >> 5;
    STAGE(0, 0);
    STAGE(1, 32);
    for (int t = 0; t < NT - 1; ++t) {
        asm volatile("s_waitcnt vmcnt(3)" ::: "memory");
        __builtin_amdgcn_s_barrier();
        if (t + 2 < NT) STAGE((t + 2) % 3, (t + 2) * 32);
        COMPUTE(t % 3);
    }
    asm volatile("s_waitcnt vmcnt(0)" ::: "memory");
    __builtin_amdgcn_s_barrier();
    COMPUTE((NT - 1) % 3);
#undef STAGE
#undef COMPUTE

    #pragma unroll
    for (int mi = 0; mi < 4; ++mi) {
        #pragma unroll
        for (int ni = 0; ni < 2; ++ni) {
            int rowb = row0 + wm * 64 + mi * 16 + g4 * 4;
            int colb = col0 + wn * 32 + ni * 16 + r;
            #pragma unroll
            for (int j = 0; j < 4; ++j)
                C[(size_t)(rowb + j) * LDC + colb] = f2h(acc[mi][ni][j]);
        }
    }
}

// ---------------- G3 with fused tail: 64 rows x 3x64 cols, grid (4,100) ----------------
__global__ __launch_bounds__(256, 3) void gemm3_fused(
    const unsigned short* __restrict__ A,      // Uh (6400 x 512)
    const unsigned short* __restrict__ BT,     // W3h (768 x 512)
    const float* __restrict__ fb1, const float* __restrict__ fb2, const float* __restrict__ fb3,
    const float* __restrict__ Wo,
    float* __restrict__ out) {
    __shared__ __align__(16) unsigned short lA[3][64 * 32];       // 12KB
    __shared__ __align__(16) unsigned short lB[3][3][64 * 32];    // 36KB -> 48KB
    int tid = threadIdx.x;
    int lane = tid & 63;
    int w = tid >> 6;
    int wm = w >> 1, wn = w & 1;
    int r = lane & 15, g4 = lane >> 4;

    constexpr int NWG = 400;
    constexpr int Q = NWG / 8;
    int flat = blockIdx.y * 4 + blockIdx.x;
    int xcd = flat & 7, idx = flat >> 3;
    int nf = xcd * Q + idx;
    int c0 = (nf % 4) * 64;
    int row0 = (nf / 4) * 64;

    f32x4 acc[3][2][2] = {};

    int rS = tid >> 2;
    int slot = tid & 3;
    int tk = (slot ^ (rS & 3)) * 8;

#define STAGE3(sel, kk) do { \
    GLOAD16(A + (size_t)(row0 + rS) * 512 + (kk) + tk, &lA[sel][tid * 8]); \
    GLOAD16(BT + (size_t)(c0 + rS) * 512 + (kk) + tk, &lB[sel][0][tid * 8]); \
    GLOAD16(BT + (size_t)(c0 + 256 + rS) * 512 + (kk) + tk, &lB[sel][1][tid * 8]); \
    GLOAD16(BT + (size_t)(c0 + 512 + rS) * 512 + (kk) + tk, &lB[sel][2][tid * 8]); \
} while (0)

    int sw = (g4 ^ (r & 3)) << 3;

#define COMPUTE3(cur) do { \
    half8 a_[2], b_[3][2]; \
    _Pragma("unroll") \
    for (int mi = 0; mi < 2; ++mi) \
        a_[mi] = *(const half8*)&lA[cur][(wm * 32 + mi * 16 + r) * 32 + sw]; \
    _Pragma("unroll") \
    for (int q = 0; q < 3; ++q) \
        _Pragma("unroll") \
        for (int ni = 0; ni < 2; ++ni) \
            b_[q][ni] = *(const half8*)&lB[cur][q][(wn * 32 + ni * 16 + r) * 32 + sw]; \
    _Pragma("unroll") \
    for (int q = 0; q < 3; ++q) \
        _Pragma("unroll") \
        for (int mi = 0; mi < 2; ++mi) \
            _Pragma("unroll") \
            for (int ni = 0; ni < 2; ++ni) \
                acc[q][mi][ni] = __builtin_amdgcn_mfma_f32_16x16x32_f16(a_[mi], b_[q][ni], acc[q][mi][ni], 0, 0, 0); \
} while (0)

    constexpr int NT = 16;
    STAGE3(0, 0);
    STAGE3(1, 32);
    for (int t = 0; t < NT - 1; ++t) {
        asm volatile("s_waitcnt vmcnt(4)" ::: "memory");
        __builtin_amdgcn_s_barrier();
        if (t + 2 < NT) STAGE3((t + 2) % 3, (t + 2) * 32);
        COMPUTE3(t % 3);
    }
    asm volatile("s_waitcnt vmcnt(0)" ::: "memory");
    __builtin_amdgcn_s_barrier();
    COMPUTE3((NT - 1) % 3);
#undef STAGE3
#undef COMPUTE3

    #pragma unroll
    for (int mi = 0; mi < 2; ++mi) {
        float v0[4] = {}, v1[4] = {}, v2[4] = {};
        #pragma unroll
        for (int ni = 0; ni < 2; ++ni) {
            int ch = c0 + wn * 32 + ni * 16 + r;
            float b1 = fb1[ch], b2 = fb2[ch], b3 = fb3[ch];
            float w0 = Wo[ch * 3 + 0], w1 = Wo[ch * 3 + 1], w2 = Wo[ch * 3 + 2];
            #pragma unroll
            for (int j = 0; j < 4; ++j) {
                float g = 1.f / (1.f + expf(-(acc[0][mi][ni][j] + b1)));
                float a2 = acc[1][mi][ni][j] + b2;
                float a3 = acc[2][mi][ni][j] + b3;
                float fused = tanhf(g * a2 + (1.f - g) * a3);
                v0[j] += fused * w0;
                v1[j] += fused * w1;
                v2[j] += fused * w2;
            }
        }
        #pragma unroll
        for (int off = 1; off < 16; off <<= 1) {
            #pragma unroll
            for (int j = 0; j < 4; ++j) {
                v0[j] += __shfl_xor(v0[j], off, 64);
                v1[j] += __shfl_xor(v1[j], off, 64);
                v2[j] += __shfl_xor(v2[j], off, 64);
            }
        }
        if (r == 0) {
            int rowb = row0 + wm * 32 + mi * 16 + g4 * 4;
            #pragma unroll
            for (int j = 0; j < 4; ++j) {
                atomicAdd(&out[(size_t)(rowb + j) * 3 + 0], v0[j]);
                atomicAdd(&out[(size_t)(rowb + j) * 3 + 1], v1[j]);
                atomicAdd(&out[(size_t)(rowb + j) * 3 + 2], v2[j]);
            }
        }
    }
}

// ---------------- layer-1 epilogue: one WAVE per node, no barriers ----------------
__global__ __launch_bounds__(256) void epi1_kernel(
    const unsigned short* __restrict__ Y1, const float* __restrict__ x,
    const float* __restrict__ bg1, const float* __restrict__ bf1, const float* __restrict__ bs1,
    const float* __restrict__ lg, const float* __restrict__ lb,
    const float* __restrict__ wsk, const float* __restrict__ bsk,
    unsigned short* __restrict__ HLh) {
    int lane = threadIdx.x & 63;
    int node = blockIdx.x * 4 + (threadIdx.x >> 6);
    size_t base = (size_t)node * 768;
    ushort4v yg = *(const ushort4v*)&Y1[base + lane * 4];
    ushort4v yf = *(const ushort4v*)&Y1[base + 256 + lane * 4];
    ushort4v ys = *(const ushort4v*)&Y1[base + 512 + lane * 4];
    float y[4];
    float s1 = 0.f, s2 = 0.f;
    #pragma unroll
    for (int cc = 0; cc < 4; cc++) {
        int o = lane * 4 + cc;
        float g = h2f(yg[cc]) + bg1[o];
        float f = h2f(yf[cc]) + bf1[o];
        float s = h2f(ys[cc]) + bs1[o];
        float gate = 1.f / (1.f + expf(-g));
        y[cc] = gate * f + (1.f - gate) * s;
        s1 += y[cc];
        s2 += y[cc] * y[cc];
    }
    #pragma unroll
    for (int off = 32; off > 0; off >>= 1) {
        s1 += __shfl_xor(s1, off, 64);
        s2 += __shfl_xor(s2, off, 64);
    }
    float mean = s1 * (1.f / 256.f);
    float var = s2 * (1.f / 256.f) - mean * mean;
    float rstd = rsqrtf(var + 1e-5f);
    float x0 = x[(size_t)(node * 12 + 11) * 2];
    float x1 = x[(size_t)(node * 12 + 11) * 2 + 1];
    unsigned short h4[4];
    #pragma unroll
    for (int cc = 0; cc < 4; cc++) {
        int o = lane * 4 + cc;
        float v = (y[cc] - mean) * rstd * lg[o] + lb[o];
        v = fmaxf(v, 0.f);
        float res = x0 * wsk[o] + x1 * wsk[256 + o] + bsk[o];
        h4[cc] = f2h(v + res);
    }
    unsigned long long pack = (unsigned long long)h4[0] | ((unsigned long long)h4[1] << 16)
                            | ((unsigned long long)h4[2] << 32) | ((unsigned long long)h4[3] << 48);
    *(unsigned long long*)&HLh[(size_t)node * 256 + lane * 4] = pack;
}

// ---------------- fused GAT: one block per node, XCD-chunked node order ----------------
__global__ __launch_bounds__(256) void gat_kernel(
    const unsigned short* __restrict__ Y2, const float* __restrict__ ef,
    const int* __restrict__ fei, const float* __restrict__ AeS,
    const int* __restrict__ cnt, const int* __restrict__ idxs, const float* __restrict__ logv,
    unsigned short* __restrict__ Uh) {
    // XCD swizzle: each XCD gets a contiguous 800-node chunk (2 batch windows ~1MB, L2-fit)
    int node = (blockIdx.x & 7) * 800 + (blockIdx.x >> 3);
    int b = node / 400, n = node % 400;
    int tid = threadIdx.x;
    __shared__ int snd[9];
    __shared__ float alf[9][8];
    __shared__ float invdf[8];
    __shared__ int jidx[64];
    __shared__ float sca[64][8];
    __shared__ float alb[64][8];
    __shared__ float invda[8];
    __shared__ float svf[9][8];
    int c = cnt[n];

    if (tid < 64) {
        int lane = tid;
        if (lane < 9) snd[lane] = fei[LL + n * 9 + lane];
        for (int e = lane; e < 72; e += 64) {
            int j = e >> 3, h = e & 7;
            int l = n * 9 + j;
            float e0 = ef[((size_t)b * LL + l) * 2];
            float e1 = ef[((size_t)b * LL + l) * 2 + 1];
            float ae = e0 * AeS[h] + e1 * AeS[8 + h];
            float aq = h2f(Y2[(size_t)node * 640 + 512 + h]);
            float ak = h2f(Y2[((size_t)(b * 400 + snd[j])) * 640 + 520 + h]);
            float s = aq + ak + ae;
            svf[j][h] = s > 0.f ? s : 0.2f * s;
        }
        if (lane < 8) {
            int h = lane;
            float mx = -1e30f;
            #pragma unroll
            for (int j = 0; j < 9; j++) mx = fmaxf(mx, svf[j][h]);
            float den = 0.f;
            #pragma unroll
            for (int j = 0; j < 9; j++) { float e = expf(svf[j][h] - mx); alf[j][h] = e; den += e; }
            invdf[h] = 1.f / fmaxf(den, 1e-12f);
        }
    } else if (tid < 128) {
        int lane = tid - 64;
        if (lane < c) jidx[lane] = idxs[n * 64 + lane];
        float jl = (lane < c) ? logv[n * 64 + lane] : 0.f;
        for (int e = lane; e < c * 8; e += 64) {
            int j = e >> 3, h = e & 7;
            float aq = h2f(Y2[(size_t)node * 640 + 528 + h]);
            float ak = h2f(Y2[((size_t)(b * 400 + jidx[j])) * 640 + 536 + h]);
            float s = aq + ak;
            s = s > 0.f ? s : 0.2f * s;
            sca[j][h] = s + __shfl(jl, j, 64);
        }
        int h = lane >> 3, grp = lane & 7;
        float mx = -1e30f;
        for (int j = grp; j < c; j += 8) mx = fmaxf(mx, sca[j][h]);
        #pragma unroll
        for (int o = 1; o < 8; o <<= 1) mx = fmaxf(mx, __shfl_xor(mx, o, 64));
        float s = 0.f;
        for (int j = grp; j < c; j += 8) { float e = expf(sca[j][h] - mx); alb[j][h] = e; s += e; }
        #pragma unroll
        for (int o = 1; o < 8; o <<= 1) s += __shfl_xor(s, o, 64);
        if (grp == 0) invda[h] = 1.f / s;
    }
    __syncthreads();

    if (tid < 128) {
        int ch = tid * 2;
        int h = ch >> 5;
        float a0 = 0.f, a1 = 0.f;
        #pragma unroll
        for (int j = 0; j < 9; j++) {
            unsigned v = *(const unsigned*)&Y2[((size_t)(b * 400 + snd[j])) * 640 + ch];
            float al = alf[j][h];
            a0 += al * h2f((unsigned short)(v & 0xffff));
            a1 += al * h2f((unsigned short)(v >> 16));
        }
        float iv = invdf[h];
        a0 *= iv; a1 *= iv;
        a0 = a0 > 0.f ? a0 : (expf(a0) - 1.f);
        a1 = a1 > 0.f ? a1 : (expf(a1) - 1.f);
        unsigned o = (unsigned)f2h(a0) | ((unsigned)f2h(a1) << 16);
        *(unsigned*)&Uh[(size_t)node * 512 + ch] = o;
    } else {
        int ch = (tid - 128) * 2;
        int h = ch >> 5;
        float a0 = 0.f, a1 = 0.f;
        for (int j = 0; j < c; j++) {
            unsigned v = *(const unsigned*)&Y2[((size_t)(b * 400 + jidx[j])) * 640 + 256 + ch];
            float al = alb[j][h];
            a0 += al * h2f((unsigned short)(v & 0xffff));
            a1 += al * h2f((unsigned short)(v >> 16));
        }
        float iv = invda[h];
        a0 *= iv; a1 *= iv;
        a0 = a0 > 0.f ? a0 : (expf(a0) - 1.f);
        a1 = a1 > 0.f ? a1 : (expf(a1) - 1.f);
        unsigned o = (unsigned)f2h(a0) | ((unsigned)f2h(a1) << 16);
        *(unsigned*)&Uh[(size_t)node * 512 + 256 + ch] = o;
    }
}

// ---------------- launcher ----------------
extern "C" void kernel_launch(void* const* d_in, const int* in_sizes, int n_in,
                              void* d_out, int out_size, void* d_ws, size_t ws_size,
                              hipStream_t stream) {
    const float* x   = (const float*)d_in[0];
    const float* ef  = (const float*)d_in[1];
    const int*   fei = (const int*)d_in[2];
    const float* wg0 = (const float*)d_in[3];
    const float* bg0 = (const float*)d_in[4];
    const float* wf0 = (const float*)d_in[5];
    const float* bf0 = (const float*)d_in[6];
    const float* ws0 = (const float*)d_in[7];
    const float* bs0 = (const float*)d_in[8];
    const float* ln0g = (const float*)d_in[9];
    const float* ln0b = (const float*)d_in[10];
    const float* wg1 = (const float*)d_in[11];
    const float* bg1 = (const float*)d_in[12];
    const float* wf1 = (const float*)d_in[13];
    const float* bf1 = (const float*)d_in[14];
    const float* ws1 = (const float*)d_in[15];
    const float* bs1 = (const float*)d_in[16];
    const float* ln1g = (const float*)d_in[17];
    const float* ln1b = (const float*)d_in[18];
    const float* wsk = (const float*)d_in[19];
    const float* bsk = (const float*)d_in[20];
    const float* sWq = (const float*)d_in[21];
    const float* sWk = (const float*)d_in[22];
    const float* sWv = (const float*)d_in[23];
    const float* sWe = (const float*)d_in[24];
    const float* saq = (const float*)d_in[25];
    const float* sak = (const float*)d_in[26];
    const float* sae = (const float*)d_in[27];
    const float* dWq = (const float*)d_in[28];
    const float* dWk = (const float*)d_in[29];
    const float* dWv = (const float*)d_in[30];
    const float* daq = (const float*)d_in[31];
    const float* dak = (const float*)d_in[32];
    const float* E1  = (const float*)d_in[33];
    const float* E2  = (const float*)d_in[34];
    const float* fW1 = (const float*)d_in[35];
    const float* fb1 = (const float*)d_in[36];
    const float* fW2 = (const float*)d_in[37];
    const float* fb2 = (const float*)d_in[38];
    const float* fW3 = (const float*)d_in[39];
    const float* fb3 = (const float*)d_in[40];
    const float* Wo  = (const float*)d_in[41];
    const float* bo  = (const float*)d_in[42];
    float* out = (float*)d_out;

    char* b = (char*)d_ws;
    unsigned short* Xh  = (unsigned short*)(b + 0);          // 9,830,400
    unsigned short* Yh  = (unsigned short*)(b + 9830400);    // 9,830,400 (Y1/Y2 fp16, reused)
    unsigned short* HLh = (unsigned short*)(b + 19660800);   // 3,276,800
    unsigned short* Uh  = (unsigned short*)(b + 22937600);   // 6,553,600
    unsigned short* W1h = (unsigned short*)(b + 29491200);   // 1,179,648
    unsigned short* W2h = (unsigned short*)(b + 30670848);   // 327,680
    unsigned short* W3h = (unsigned short*)(b + 30998528);   // 786,432
    float*          AES = (float*)(b + 31784960);            // 64 (+pad)
    float*          LOGV= (float*)(b + 31785216);            // 102,400
    int*            CNT = (int*)(b + 31887616);              // 1,600
    int*            IDX = (int*)(b + 31889216);              // 102,400

    prep_kernel<<<6256, 256, 0, stream>>>(
        wg1, wf1, ws1,
        sWv, dWv, sWq, saq, sWk, sak, dWq, daq, dWk, dak,
        fW1, fW2, fW3, sWe, sae, E1, E2,
        x, wg0, bg0, wf0, bf0, ws0, bs0, ln0g, ln0b, bo,
        W1h, W2h, W3h, AES,
        CNT, IDX, LOGV, Xh, out);

    // G1: Y1 = X @ W1  (M=6400, N=768, K=768) -> fp16, 128x64 tiles
    gemm_f16_big<768, 768, 12, 50><<<dim3(12, 50), 256, 0, stream>>>(Xh, W1h, Yh);

    // epi1: one wave per node
    epi1_kernel<<<1600, 256, 0, stream>>>(Yh, x, bg1, bf1, bs1, ln1g, ln1b, wsk, bsk, HLh);

    // G2: Y2 = HL @ W2 (M=6400, N=576 used, K=256) -> fp16, 128x64 tiles
    gemm_f16_big<256, 640, 9, 50><<<dim3(9, 50), 256, 0, stream>>>(HLh, W2h, Yh);

    // fused attention stages -> U (one block per node, XCD-chunked)
    gat_kernel<<<NODES, 256, 0, stream>>>(Yh, ef, fei, AES, CNT, IDX, LOGV, Uh);

    // G3 + fused tail: out += tanh-fuse(U @ W3) @ Wo
    gemm3_fused<<<dim3(4, 100), 256, 0, stream>>>(Uh, W3h, fb1, fb2, fb3, Wo, out);
}

// Round 14
// 92.811 us; speedup vs baseline: 1.1184x; 1.0129x over previous
//
#include <hip/hip_runtime.h>
#include <math.h>

// Problem constants
#define LL 3600
#define NODES 6400

typedef __attribute__((ext_vector_type(8))) _Float16 half8;
typedef __attribute__((ext_vector_type(4))) float f32x4;
typedef __attribute__((ext_vector_type(4))) unsigned short ushort4v;

// ---------------- fp16 helpers ----------------
__device__ __forceinline__ unsigned short f2h(float f) {
    union { _Float16 h; unsigned short u; } cv;
    cv.h = (_Float16)f;
    return cv.u;
}
__device__ __forceinline__ float h2f(unsigned short u) {
    union { unsigned short u; _Float16 h; } cv;
    cv.u = u;
    return (float)cv.h;
}

#define GLOAD16(gp, lp) __builtin_amdgcn_global_load_lds( \
    (const __attribute__((address_space(1))) unsigned int*)(const void*)(gp), \
    (__attribute__((address_space(3))) unsigned int*)(void*)(lp), 16, 0, 0)

// ================= MEGA PREP KERNEL =================
// blocks [0,2304): W1T | [2304,2944): W2T | [2944,4480): W3T
// [4480]: AeS | [4481,4581): adj | [4581,6181): tcn0 | [6181,6256): out bias-init
__global__ __launch_bounds__(256) void prep_kernel(
    const float* __restrict__ wg1, const float* __restrict__ wf1, const float* __restrict__ ws1,
    const float* __restrict__ sWv, const float* __restrict__ dWv,
    const float* __restrict__ sWq, const float* __restrict__ saq,
    const float* __restrict__ sWk, const float* __restrict__ sak,
    const float* __restrict__ dWq, const float* __restrict__ daq,
    const float* __restrict__ dWk, const float* __restrict__ dak,
    const float* __restrict__ fW1, const float* __restrict__ fW2, const float* __restrict__ fW3,
    const float* __restrict__ sWe, const float* __restrict__ sae,
    const float* __restrict__ E1, const float* __restrict__ E2,
    const float* __restrict__ x,
    const float* __restrict__ wg0, const float* __restrict__ bg0,
    const float* __restrict__ wf0, const float* __restrict__ bf0,
    const float* __restrict__ ws0, const float* __restrict__ bs0,
    const float* __restrict__ lg0, const float* __restrict__ lb0,
    const float* __restrict__ bo,
    unsigned short* __restrict__ W1h,
    unsigned short* __restrict__ W2h,
    unsigned short* __restrict__ W3h,
    float* __restrict__ AeS,
    int* __restrict__ cnt, int* __restrict__ idxs, float* __restrict__ logv,
    unsigned short* __restrict__ Xh,
    float* __restrict__ out) {
    int bid = blockIdx.x;
    int tid = threadIdx.x;

    if (bid < 2304) {
        int idx = bid * 256 + tid;
        int n = idx / 768, k = idx % 768;
        int which = n >> 8, o = n & 255;
        int tt = k >> 8, i = k & 255;
        const float* w = which == 0 ? wg1 : (which == 1 ? wf1 : ws1);
        W1h[idx] = f2h(w[(o * 256 + i) * 3 + tt]);
    } else if (bid < 2944) {
        int idx = (bid - 2304) * 256 + tid;
        int n = idx / 256, k = idx % 256;
        float v = 0.f;
        if (n < 256) v = sWv[k * 256 + n];
        else if (n < 512) v = dWv[k * 256 + (n - 256)];
        else if (n < 544) {
            int j = n - 512, g = j >> 3, h = j & 7;
            const float* Wm = g == 0 ? sWq : (g == 1 ? sWk : (g == 2 ? dWq : dWk));
            const float* am = g == 0 ? saq : (g == 1 ? sak : (g == 2 ? daq : dak));
            float s = 0.f;
            for (int d = 0; d < 32; d++) s += Wm[k * 256 + h * 32 + d] * am[h * 32 + d];
            v = s;
        }
        W2h[idx] = f2h(v);
    } else if (bid < 4480) {
        int idx = (bid - 2944) * 256 + tid;
        int n = idx / 512, k = idx % 512;
        float v = 0.f;
        if (k < 256) {
            if (n < 256) v = fW1[k * 256 + n];
            else if (n < 512) v = fW2[k * 256 + (n - 256)];
        } else {
            int c = k - 256;
            if (n < 256) v = fW1[c * 256 + n];
            else if (n >= 512) v = fW3[c * 256 + (n - 512)];
        }
        W3h[idx] = f2h(v);
    } else if (bid == 4480) {
        if (tid < 16) {
            int cc = tid / 8, h = tid % 8;
            float s = 0.f;
            for (int d = 0; d < 32; d++) s += sWe[cc * 256 + h * 32 + d] * sae[h * 32 + d];
            AeS[tid] = s;
        }
    } else if (bid < 4581) {
        // ---- adjacency: one wave per row
        int n = ((bid - 4481) * 256 + tid) >> 6;
        int lane = tid & 63;
        if (n >= 400) return;
        float e1[10];
        #pragma unroll
        for (int k = 0; k < 10; k++) e1[k] = E1[n * 10 + k];
        float p[7];
        #pragma unroll
        for (int i = 0; i < 7; i++) {
            int j = i * 64 + lane;
            if (j < 400) {
                float s = 0.f;
                #pragma unroll
                for (int k = 0; k < 10; k++) s += e1[k] * E2[j * 10 + k];
                p[i] = fmaxf(s, 0.f);
            } else p[i] = -1e30f;
        }
        float mx = -1e30f;
        #pragma unroll
        for (int i = 0; i < 7; i++) mx = fmaxf(mx, p[i]);
        #pragma unroll
        for (int o = 32; o > 0; o >>= 1) mx = fmaxf(mx, __shfl_xor(mx, o, 64));
        float sum = 0.f;
        #pragma unroll
        for (int i = 0; i < 7; i++) {
            int j = i * 64 + lane;
            if (j < 400) { p[i] = expf(p[i] - mx); sum += p[i]; }
        }
        #pragma unroll
        for (int o = 32; o > 0; o >>= 1) sum += __shfl_xor(sum, o, 64);
        float inv = 1.f / sum;
        float m[7];
        #pragma unroll
        for (int i = 0; i < 7; i++) {
            int j = i * 64 + lane;
            if (j < 400) { p[i] *= inv; m[i] = p[i]; }
            else m[i] = -1e30f;
        }
        for (int it = 0; it < 15; ++it) {
            float lm = m[0];
            #pragma unroll
            for (int i = 1; i < 7; i++) lm = fmaxf(lm, m[i]);
            float gm = lm;
            #pragma unroll
            for (int o = 32; o > 0; o >>= 1) gm = fmaxf(gm, __shfl_xor(gm, o, 64));
            unsigned long long msk = __ballot(lm == gm);
            int first = (int)(__ffsll((long long)msk)) - 1;
            if (lane == first) {
                #pragma unroll
                for (int i = 0; i < 7; i++) {
                    if (m[i] == gm) { m[i] = -1e30f; break; }
                }
            }
        }
        float kth = m[0];
        #pragma unroll
        for (int i = 1; i < 7; i++) kth = fmaxf(kth, m[i]);
        #pragma unroll
        for (int o = 32; o > 0; o >>= 1) kth = fmaxf(kth, __shfl_xor(kth, o, 64));
        int base = 0;
        #pragma unroll
        for (int i = 0; i < 7; i++) {
            int j = i * 64 + lane;
            bool pred = (j < 400) && (p[i] >= kth);
            unsigned long long msk = __ballot(pred);
            int pre = __popcll(msk & ((lane == 63) ? 0x7fffffffffffffffull : ((1ull << lane) - 1)));
            if (pred) {
                int pos = base + pre;
                if (pos < 64) {
                    idxs[n * 64 + pos] = j;
                    logv[n * 64 + pos] = logf(fmaxf(p[i], 1e-12f));
                }
            }
            base += __popcll(msk);
        }
        if (lane == 0) cnt[n] = base < 64 ? base : 64;
    } else if (bid < 6181) {
        // ---- TCN layer 0: one WAVE per node, 4 channels per lane, no barriers
        int lane = tid & 63;
        int node = (bid - 4581) * 4 + (tid >> 6);
        float xs[14];
        #pragma unroll
        for (int t = 0; t < 7; t++) {
            xs[t * 2]     = x[(size_t)(node * 12 + 5 + t) * 2];
            xs[t * 2 + 1] = x[(size_t)(node * 12 + 5 + t) * 2 + 1];
        }
        float wg[4][6], wf[4][6], wsv[4][6], bgv[4], bfv[4], bsv[4], gln[4], bln[4];
        #pragma unroll
        for (int cc = 0; cc < 4; cc++) {
            int o = lane * 4 + cc;
            #pragma unroll
            for (int i = 0; i < 6; i++) {
                wg[cc][i] = wg0[o * 6 + i];
                wf[cc][i] = wf0[o * 6 + i];
                wsv[cc][i] = ws0[o * 6 + i];
            }
            bgv[cc] = bg0[o]; bfv[cc] = bf0[o]; bsv[cc] = bs0[o];
            gln[cc] = lg0[o]; bln[cc] = lb0[o];
        }
        #pragma unroll
        for (int tt = 0; tt < 3; tt++) {
            int tb = 2 * tt;
            float y[4];
            float s1 = 0.f, s2 = 0.f;
            #pragma unroll
            for (int cc = 0; cc < 4; cc++) {
                float g = bgv[cc], f = bfv[cc], s = bsv[cc];
                #pragma unroll
                for (int k = 0; k < 3; k++) {
                    #pragma unroll
                    for (int c = 0; c < 2; c++) {
                        float xv = xs[(tb + k) * 2 + c];
                        g += wg[cc][c * 3 + k] * xv;
                        f += wf[cc][c * 3 + k] * xv;
                        s += wsv[cc][c * 3 + k] * xv;
                    }
                }
                float gate = 1.f / (1.f + expf(-g));
                y[cc] = gate * f + (1.f - gate) * s;
                s1 += y[cc];
                s2 += y[cc] * y[cc];
            }
            #pragma unroll
            for (int o = 32; o > 0; o >>= 1) {
                s1 += __shfl_xor(s1, o, 64);
                s2 += __shfl_xor(s2, o, 64);
            }
            float mean = s1 * (1.f / 256.f);
            float var = s2 * (1.f / 256.f) - mean * mean;
            float rstd = rsqrtf(var + 1e-5f);
            unsigned short h4[4];
            #pragma unroll
            for (int cc = 0; cc < 4; cc++) {
                float v = (y[cc] - mean) * rstd * gln[cc] + bln[cc];
                h4[cc] = f2h(fmaxf(v, 0.f));
            }
            unsigned long long pack = (unsigned long long)h4[0] | ((unsigned long long)h4[1] << 16)
                                    | ((unsigned long long)h4[2] << 32) | ((unsigned long long)h4[3] << 48);
            *(unsigned long long*)&Xh[(size_t)node * 768 + tt * 256 + lane * 4] = pack;
        }
    } else {
        int idx = (bid - 6181) * 256 + tid;
        if (idx < NODES * 3) out[idx] = bo[idx % 3];
    }
}

// ---------------- fp16 MFMA GEMM, 64x64 tile, BK=64, 3-stage counted-vmcnt ----------------
// 4 waves as 2x2; each wave 32x32 (2x2 frags x 2 k-slices = 8 MFMA/step). 12 barriers at K=768.
template<int K, int LDC, int GX, int GY>
__global__ __launch_bounds__(256, 3) void gemm_f16_k64(
    const unsigned short* __restrict__ A,
    const unsigned short* __restrict__ BT,
    unsigned short* __restrict__ C) {
    __shared__ __align__(16) unsigned short lA[3][64 * 64];    // 8KB/buf
    __shared__ __align__(16) unsigned short lB[3][64 * 64];    // 8KB/buf -> 48KB total
    int tid = threadIdx.x;
    int lane = tid & 63;
    int w = tid >> 6;
    int wm = w >> 1, wn = w & 1;
    int r = lane & 15, g4 = lane >> 4;

    constexpr int NWG = GX * GY;
    constexpr int Q = NWG / 8, R = NWG % 8;
    int flat = blockIdx.y * GX + blockIdx.x;
    int xcd = flat & 7, idx = flat >> 3;
    int nf = (xcd < R ? xcd * (Q + 1) : R * (Q + 1) + (xcd - R) * Q) + idx;
    int col0 = (nf % GX) * 64;
    int row0 = (nf / GX) * 64;

    f32x4 acc[2][2] = {};

    // staging: 64 rows x 64 halves = 256 16B-chunks per array, 1 per thread
    int rS = tid >> 3;                  // 0..31? no: 256 threads / 8 slots... recompute:
    // row has 64 halves = 128B = 8 x 16B slots. 64 rows x 8 slots = 512 chunks... 2 arrays
    // -> thread handles 1 chunk of A and 1 of B: chunk id = tid (A), tid (B); row = tid>>3? 256/8=32 rows... need 64 rows.
    // Use: chunk c in [0,512): first 256 = A, by thread; row = tid>>2? 
    // Simpler: each thread loads 2 chunks of combined space? A: 512 chunks needs 2/thread.
    int rA0 = tid >> 3, sl0 = tid & 7;             // rows 0..31
    int rA1 = 32 + (tid >> 3);                     // rows 32..63
    int tk0 = (sl0 ^ (rA0 & 7)) * 8;               // swizzled 16B slot (8 halves)
    int tk1 = (sl0 ^ (rA1 & 7)) * 8;

#define STAGE(sel, kk) do { \
    GLOAD16(A + (size_t)(row0 + rA0) * K + (kk) + tk0, &lA[sel][(rA0 * 8 + sl0) * 8]); \
    GLOAD16(A + (size_t)(row0 + rA1) * K + (kk) + tk1, &lA[sel][(rA1 * 8 + sl0) * 8]); \
    GLOAD16(BT + (size_t)(col0 + rA0) * K + (kk) + tk0, &lB[sel][(rA0 * 8 + sl0) * 8]); \
    GLOAD16(BT + (size_t)(col0 + rA1) * K + (kk) + tk1, &lB[sel][(rA1 * 8 + sl0) * 8]); \
} while (0)

#define COMPUTE(cur) do { \
    _Pragma("unroll") \
    for (int ks = 0; ks < 2; ++ks) { \
        int sw = ((ks * 4 + g4) ^ (r & 7)) << 3; \
        half8 a_[2], b_[2]; \
        _Pragma("unroll") \
        for (int mi = 0; mi < 2; ++mi) \
            a_[mi] = *(const half8*)&lA[cur][(wm * 32 + mi * 16 + r) * 64 + sw]; \
        _Pragma("unroll") \
        for (int ni = 0; ni < 2; ++ni) \
            b_[ni] = *(const half8*)&lB[cur][(wn * 32 + ni * 16 + r) * 64 + sw]; \
        _Pragma("unroll") \
        for (int mi = 0; mi < 2; ++mi) \
            _Pragma("unroll") \
            for (int ni = 0; ni < 2; ++ni) \
                acc[mi][ni] = __builtin_amdgcn_mfma_f32_16x16x32_f16(a_[mi], b_[ni], acc[mi][ni], 0, 0, 0); \
    } \
} while (0)

    constexpr int NT = K >> 6;
    STAGE(0, 0);
    STAGE(1, 64);
    for (int t = 0; t < NT - 1; ++t) {
        asm volatile("s_waitcnt vmcnt(4)" ::: "memory");
        __builtin_amdgcn_s_barrier();
        if (t + 2 < NT) STAGE((t + 2) % 3, (t + 2) * 64);
        COMPUTE(t % 3);
    }
    asm volatile("s_waitcnt vmcnt(0)" ::: "memory");
    __builtin_amdgcn_s_barrier();
    COMPUTE((NT - 1) % 3);
#undef STAGE
#undef COMPUTE

    #pragma unroll
    for (int mi = 0; mi < 2; ++mi) {
        #pragma unroll
        for (int ni = 0; ni < 2; ++ni) {
            int rowb = row0 + wm * 32 + mi * 16 + g4 * 4;
            int colb = col0 + wn * 32 + ni * 16 + r;
            #pragma unroll
            for (int j = 0; j < 4; ++j)
                C[(size_t)(rowb + j) * LDC + colb] = f2h(acc[mi][ni][j]);
        }
    }
}

// ---------------- fp16 MFMA GEMM, 128x64 tile, BK=32, 3-stage counted-vmcnt ----------------
template<int K, int LDC, int GX, int GY>
__global__ __launch_bounds__(256, 4) void gemm_f16_big(
    const unsigned short* __restrict__ A,
    const unsigned short* __restrict__ BT,
    unsigned short* __restrict__ C) {
    __shared__ __align__(16) unsigned short lA[3][128 * 32];   // 24KB
    __shared__ __align__(16) unsigned short lB[3][64 * 32];    // 12KB -> 36KB
    int tid = threadIdx.x;
    int lane = tid & 63;
    int w = tid >> 6;
    int wm = w >> 1, wn = w & 1;
    int r = lane & 15, g4 = lane >> 4;

    constexpr int NWG = GX * GY;
    constexpr int Q = NWG / 8, R = NWG % 8;
    int flat = blockIdx.y * GX + blockIdx.x;
    int xcd = flat & 7, idx = flat >> 3;
    int nf = (xcd < R ? xcd * (Q + 1) : R * (Q + 1) + (xcd - R) * Q) + idx;
    int col0 = (nf % GX) * 64;
    int row0 = (nf / GX) * 128;

    f32x4 acc[4][2] = {};

    int rS = tid >> 2;
    int slot = tid & 3;
    int tkA0 = (slot ^ (rS & 3)) * 8;
    int tkA1 = (slot ^ ((rS + 64) & 3)) * 8;
    int tkB = tkA0;

#define STAGE(sel, kk) do { \
    GLOAD16(A + (size_t)(row0 + rS) * K + (kk) + tkA0, &lA[sel][tid * 8]); \
    GLOAD16(A + (size_t)(row0 + 64 + rS) * K + (kk) + tkA1, &lA[sel][(tid + 256) * 8]); \
    GLOAD16(BT + (size_t)(col0 + rS) * K + (kk) + tkB, &lB[sel][tid * 8]); \
} while (0)

    int sw = (g4 ^ (r & 3)) << 3;

#define COMPUTE(cur) do { \
    half8 a_[4], b_[2]; \
    _Pragma("unroll") \
    for (int mi = 0; mi < 4; ++mi) \
        a_[mi] = *(const half8*)&lA[cur][(wm * 64 + mi * 16 + r) * 32 + sw]; \
    _Pragma("unroll") \
    for (int ni = 0; ni < 2; ++ni) \
        b_[ni] = *(const half8*)&lB[cur][(wn * 32 + ni * 16 + r) * 32 + sw]; \
    _Pragma("unroll") \
    for (int mi = 0; mi < 4; ++mi) \
        _Pragma("unroll") \
        for (int ni = 0; ni < 2; ++ni) \
            acc[mi][ni] = __builtin_amdgcn_mfma_f32_16x16x32_f16(a_[mi], b_[ni], acc[mi][ni], 0, 0, 0); \
} while (0)

    constexpr int NT = K >> 5;
    STAGE(0, 0);
    STAGE(1, 32);
    for (int t = 0; t < NT - 1; ++t) {
        asm volatile("s_waitcnt vmcnt(3)" ::: "memory");
        __builtin_amdgcn_s_barrier();
        if (t + 2 < NT) STAGE((t + 2) % 3, (t + 2) * 32);
        COMPUTE(t % 3);
    }
    asm volatile("s_waitcnt vmcnt(0)" ::: "memory");
    __builtin_amdgcn_s_barrier();
    COMPUTE((NT - 1) % 3);
#undef STAGE
#undef COMPUTE

    #pragma unroll
    for (int mi = 0; mi < 4; ++mi) {
        #pragma unroll
        for (int ni = 0; ni < 2; ++ni) {
            int rowb = row0 + wm * 64 + mi * 16 + g4 * 4;
            int colb = col0 + wn * 32 + ni * 16 + r;
            #pragma unroll
            for (int j = 0; j < 4; ++j)
                C[(size_t)(rowb + j) * LDC + colb] = f2h(acc[mi][ni][j]);
        }
    }
}

// ---------------- G3 with fused tail: 64 rows x 3x64 cols, grid (4,100) ----------------
__global__ __launch_bounds__(256, 3) void gemm3_fused(
    const unsigned short* __restrict__ A,      // Uh (6400 x 512)
    const unsigned short* __restrict__ BT,     // W3h (768 x 512)
    const float* __restrict__ fb1, const float* __restrict__ fb2, const float* __restrict__ fb3,
    const float* __restrict__ Wo,
    float* __restrict__ out) {
    __shared__ __align__(16) unsigned short lA[3][64 * 32];       // 12KB
    __shared__ __align__(16) unsigned short lB[3][3][64 * 32];    // 36KB -> 48KB
    int tid = threadIdx.x;
    int lane = tid & 63;
    int w = tid >> 6;
    int wm = w >> 1, wn = w & 1;
    int r = lane & 15, g4 = lane >> 4;

    constexpr int NWG = 400;
    constexpr int Q = NWG / 8;
    int flat = blockIdx.y * 4 + blockIdx.x;
    int xcd = flat & 7, idx = flat >> 3;
    int nf = xcd * Q + idx;
    int c0 = (nf % 4) * 64;
    int row0 = (nf / 4) * 64;

    f32x4 acc[3][2][2] = {};

    int rS = tid >> 2;
    int slot = tid & 3;
    int tk = (slot ^ (rS & 3)) * 8;

#define STAGE3(sel, kk) do { \
    GLOAD16(A + (size_t)(row0 + rS) * 512 + (kk) + tk, &lA[sel][tid * 8]); \
    GLOAD16(BT + (size_t)(c0 + rS) * 512 + (kk) + tk, &lB[sel][0][tid * 8]); \
    GLOAD16(BT + (size_t)(c0 + 256 + rS) * 512 + (kk) + tk, &lB[sel][1][tid * 8]); \
    GLOAD16(BT + (size_t)(c0 + 512 + rS) * 512 + (kk) + tk, &lB[sel][2][tid * 8]); \
} while (0)

    int sw = (g4 ^ (r & 3)) << 3;

#define COMPUTE3(cur) do { \
    half8 a_[2], b_[3][2]; \
    _Pragma("unroll") \
    for (int mi = 0; mi < 2; ++mi) \
        a_[mi] = *(const half8*)&lA[cur][(wm * 32 + mi * 16 + r) * 32 + sw]; \
    _Pragma("unroll") \
    for (int q = 0; q < 3; ++q) \
        _Pragma("unroll") \
        for (int ni = 0; ni < 2; ++ni) \
            b_[q][ni] = *(const half8*)&lB[cur][q][(wn * 32 + ni * 16 + r) * 32 + sw]; \
    _Pragma("unroll") \
    for (int q = 0; q < 3; ++q) \
        _Pragma("unroll") \
        for (int mi = 0; mi < 2; ++mi) \
            _Pragma("unroll") \
            for (int ni = 0; ni < 2; ++ni) \
                acc[q][mi][ni] = __builtin_amdgcn_mfma_f32_16x16x32_f16(a_[mi], b_[q][ni], acc[q][mi][ni], 0, 0, 0); \
} while (0)

    constexpr int NT = 16;
    STAGE3(0, 0);
    STAGE3(1, 32);
    for (int t = 0; t < NT - 1; ++t) {
        asm volatile("s_waitcnt vmcnt(4)" ::: "memory");
        __builtin_amdgcn_s_barrier();
        if (t + 2 < NT) STAGE3((t + 2) % 3, (t + 2) * 32);
        COMPUTE3(t % 3);
    }
    asm volatile("s_waitcnt vmcnt(0)" ::: "memory");
    __builtin_amdgcn_s_barrier();
    COMPUTE3((NT - 1) % 3);
#undef STAGE3
#undef COMPUTE3

    #pragma unroll
    for (int mi = 0; mi < 2; ++mi) {
        float v0[4] = {}, v1[4] = {}, v2[4] = {};
        #pragma unroll
        for (int ni = 0; ni < 2; ++ni) {
            int ch = c0 + wn * 32 + ni * 16 + r;
            float b1 = fb1[ch], b2 = fb2[ch], b3 = fb3[ch];
            float w0 = Wo[ch * 3 + 0], w1 = Wo[ch * 3 + 1], w2 = Wo[ch * 3 + 2];
            #pragma unroll
            for (int j = 0; j < 4; ++j) {
                float g = 1.f / (1.f + expf(-(acc[0][mi][ni][j] + b1)));
                float a2 = acc[1][mi][ni][j] + b2;
                float a3 = acc[2][mi][ni][j] + b3;
                float fused = tanhf(g * a2 + (1.f - g) * a3);
                v0[j] += fused * w0;
                v1[j] += fused * w1;
                v2[j] += fused * w2;
            }
        }
        #pragma unroll
        for (int off = 1; off < 16; off <<= 1) {
            #pragma unroll
            for (int j = 0; j < 4; ++j) {
                v0[j] += __shfl_xor(v0[j], off, 64);
                v1[j] += __shfl_xor(v1[j], off, 64);
                v2[j] += __shfl_xor(v2[j], off, 64);
            }
        }
        if (r == 0) {
            int rowb = row0 + wm * 32 + mi * 16 + g4 * 4;
            #pragma unroll
            for (int j = 0; j < 4; ++j) {
                atomicAdd(&out[(size_t)(rowb + j) * 3 + 0], v0[j]);
                atomicAdd(&out[(size_t)(rowb + j) * 3 + 1], v1[j]);
                atomicAdd(&out[(size_t)(rowb + j) * 3 + 2], v2[j]);
            }
        }
    }
}

// ---------------- layer-1 epilogue: one WAVE per node, no barriers ----------------
__global__ __launch_bounds__(256) void epi1_kernel(
    const unsigned short* __restrict__ Y1, const float* __restrict__ x,
    const float* __restrict__ bg1, const float* __restrict__ bf1, const float* __restrict__ bs1,
    const float* __restrict__ lg, const float* __restrict__ lb,
    const float* __restrict__ wsk, const float* __restrict__ bsk,
    unsigned short* __restrict__ HLh) {
    int lane = threadIdx.x & 63;
    int node = blockIdx.x * 4 + (threadIdx.x >> 6);
    size_t base = (size_t)node * 768;
    ushort4v yg = *(const ushort4v*)&Y1[base + lane * 4];
    ushort4v yf = *(const ushort4v*)&Y1[base + 256 + lane * 4];
    ushort4v ys = *(const ushort4v*)&Y1[base + 512 + lane * 4];
    float y[4];
    float s1 = 0.f, s2 = 0.f;
    #pragma unroll
    for (int cc = 0; cc < 4; cc++) {
        int o = lane * 4 + cc;
        float g = h2f(yg[cc]) + bg1[o];
        float f = h2f(yf[cc]) + bf1[o];
        float s = h2f(ys[cc]) + bs1[o];
        float gate = 1.f / (1.f + expf(-g));
        y[cc] = gate * f + (1.f - gate) * s;
        s1 += y[cc];
        s2 += y[cc] * y[cc];
    }
    #pragma unroll
    for (int off = 32; off > 0; off >>= 1) {
        s1 += __shfl_xor(s1, off, 64);
        s2 += __shfl_xor(s2, off, 64);
    }
    float mean = s1 * (1.f / 256.f);
    float var = s2 * (1.f / 256.f) - mean * mean;
    float rstd = rsqrtf(var + 1e-5f);
    float x0 = x[(size_t)(node * 12 + 11) * 2];
    float x1 = x[(size_t)(node * 12 + 11) * 2 + 1];
    unsigned short h4[4];
    #pragma unroll
    for (int cc = 0; cc < 4; cc++) {
        int o = lane * 4 + cc;
        float v = (y[cc] - mean) * rstd * lg[o] + lb[o];
        v = fmaxf(v, 0.f);
        float res = x0 * wsk[o] + x1 * wsk[256 + o] + bsk[o];
        h4[cc] = f2h(v + res);
    }
    unsigned long long pack = (unsigned long long)h4[0] | ((unsigned long long)h4[1] << 16)
                            | ((unsigned long long)h4[2] << 32) | ((unsigned long long)h4[3] << 48);
    *(unsigned long long*)&HLh[(size_t)node * 256 + lane * 4] = pack;
}

// ---------------- fused GAT: one block per node, XCD-chunked node order ----------------
__global__ __launch_bounds__(256) void gat_kernel(
    const unsigned short* __restrict__ Y2, const float* __restrict__ ef,
    const int* __restrict__ fei, const float* __restrict__ AeS,
    const int* __restrict__ cnt, const int* __restrict__ idxs, const float* __restrict__ logv,
    unsigned short* __restrict__ Uh) {
    int node = (blockIdx.x & 7) * 800 + (blockIdx.x >> 3);
    int b = node / 400, n = node % 400;
    int tid = threadIdx.x;
    __shared__ int snd[9];
    __shared__ float alf[9][8];
    __shared__ float invdf[8];
    __shared__ int jidx[64];
    __shared__ float sca[64][8];
    __shared__ float alb[64][8];
    __shared__ float invda[8];
    __shared__ float svf[9][8];
    int c = cnt[n];

    if (tid < 64) {
        int lane = tid;
        if (lane < 9) snd[lane] = fei[LL + n * 9 + lane];
        for (int e = lane; e < 72; e += 64) {
            int j = e >> 3, h = e & 7;
            int l = n * 9 + j;
            float e0 = ef[((size_t)b * LL + l) * 2];
            float e1 = ef[((size_t)b * LL + l) * 2 + 1];
            float ae = e0 * AeS[h] + e1 * AeS[8 + h];
            float aq = h2f(Y2[(size_t)node * 640 + 512 + h]);
            float ak = h2f(Y2[((size_t)(b * 400 + snd[j])) * 640 + 520 + h]);
            float s = aq + ak + ae;
            svf[j][h] = s > 0.f ? s : 0.2f * s;
        }
        if (lane < 8) {
            int h = lane;
            float mx = -1e30f;
            #pragma unroll
            for (int j = 0; j < 9; j++) mx = fmaxf(mx, svf[j][h]);
            float den = 0.f;
            #pragma unroll
            for (int j = 0; j < 9; j++) { float e = expf(svf[j][h] - mx); alf[j][h] = e; den += e; }
            invdf[h] = 1.f / fmaxf(den, 1e-12f);
        }
    } else if (tid < 128) {
        int lane = tid - 64;
        if (lane < c) jidx[lane] = idxs[n * 64 + lane];
        float jl = (lane < c) ? logv[n * 64 + lane] : 0.f;
        for (int e = lane; e < c * 8; e += 64) {
            int j = e >> 3, h = e & 7;
            float aq = h2f(Y2[(size_t)node * 640 + 528 + h]);
            float ak = h2f(Y2[((size_t)(b * 400 + jidx[j])) * 640 + 536 + h]);
            float s = aq + ak;
            s = s > 0.f ? s : 0.2f * s;
            sca[j][h] = s + __shfl(jl, j, 64);
        }
        int h = lane >> 3, grp = lane & 7;
        float mx = -1e30f;
        for (int j = grp; j < c; j += 8) mx = fmaxf(mx, sca[j][h]);
        #pragma unroll
        for (int o = 1; o < 8; o <<= 1) mx = fmaxf(mx, __shfl_xor(mx, o, 64));
        float s = 0.f;
        for (int j = grp; j < c; j += 8) { float e = expf(sca[j][h] - mx); alb[j][h] = e; s += e; }
        #pragma unroll
        for (int o = 1; o < 8; o <<= 1) s += __shfl_xor(s, o, 64);
        if (grp == 0) invda[h] = 1.f / s;
    }
    __syncthreads();

    if (tid < 128) {
        int ch = tid * 2;
        int h = ch >> 5;
        float a0 = 0.f, a1 = 0.f;
        #pragma unroll
        for (int j = 0; j < 9; j++) {
            unsigned v = *(const unsigned*)&Y2[((size_t)(b * 400 + snd[j])) * 640 + ch];
            float al = alf[j][h];
            a0 += al * h2f((unsigned short)(v & 0xffff));
            a1 += al * h2f((unsigned short)(v >> 16));
        }
        float iv = invdf[h];
        a0 *= iv; a1 *= iv;
        a0 = a0 > 0.f ? a0 : (expf(a0) - 1.f);
        a1 = a1 > 0.f ? a1 : (expf(a1) - 1.f);
        unsigned o = (unsigned)f2h(a0) | ((unsigned)f2h(a1) << 16);
        *(unsigned*)&Uh[(size_t)node * 512 + ch] = o;
    } else {
        int ch = (tid - 128) * 2;
        int h = ch >> 5;
        float a0 = 0.f, a1 = 0.f;
        for (int j = 0; j < c; j++) {
            unsigned v = *(const unsigned*)&Y2[((size_t)(b * 400 + jidx[j])) * 640 + 256 + ch];
            float al = alb[j][h];
            a0 += al * h2f((unsigned short)(v & 0xffff));
            a1 += al * h2f((unsigned short)(v >> 16));
        }
        float iv = invda[h];
        a0 *= iv; a1 *= iv;
        a0 = a0 > 0.f ? a0 : (expf(a0) - 1.f);
        a1 = a1 > 0.f ? a1 : (expf(a1) - 1.f);
        unsigned o = (unsigned)f2h(a0) | ((unsigned)f2h(a1) << 16);
        *(unsigned*)&Uh[(size_t)node * 512 + 256 + ch] = o;
    }
}

// ---------------- launcher ----------------
extern "C" void kernel_launch(void* const* d_in, const int* in_sizes, int n_in,
                              void* d_out, int out_size, void* d_ws, size_t ws_size,
                              hipStream_t stream) {
    const float* x   = (const float*)d_in[0];
    const float* ef  = (const float*)d_in[1];
    const int*   fei = (const int*)d_in[2];
    const float* wg0 = (const float*)d_in[3];
    const float* bg0 = (const float*)d_in[4];
    const float* wf0 = (const float*)d_in[5];
    const float* bf0 = (const float*)d_in[6];
    const float* ws0 = (const float*)d_in[7];
    const float* bs0 = (const float*)d_in[8];
    const float* ln0g = (const float*)d_in[9];
    const float* ln0b = (const float*)d_in[10];
    const float* wg1 = (const float*)d_in[11];
    const float* bg1 = (const float*)d_in[12];
    const float* wf1 = (const float*)d_in[13];
    const float* bf1 = (const float*)d_in[14];
    const float* ws1 = (const float*)d_in[15];
    const float* bs1 = (const float*)d_in[16];
    const float* ln1g = (const float*)d_in[17];
    const float* ln1b = (const float*)d_in[18];
    const float* wsk = (const float*)d_in[19];
    const float* bsk = (const float*)d_in[20];
    const float* sWq = (const float*)d_in[21];
    const float* sWk = (const float*)d_in[22];
    const float* sWv = (const float*)d_in[23];
    const float* sWe = (const float*)d_in[24];
    const float* saq = (const float*)d_in[25];
    const float* sak = (const float*)d_in[26];
    const float* sae = (const float*)d_in[27];
    const float* dWq = (const float*)d_in[28];
    const float* dWk = (const float*)d_in[29];
    const float* dWv = (const float*)d_in[30];
    const float* daq = (const float*)d_in[31];
    const float* dak = (const float*)d_in[32];
    const float* E1  = (const float*)d_in[33];
    const float* E2  = (const float*)d_in[34];
    const float* fW1 = (const float*)d_in[35];
    const float* fb1 = (const float*)d_in[36];
    const float* fW2 = (const float*)d_in[37];
    const float* fb2 = (const float*)d_in[38];
    const float* fW3 = (const float*)d_in[39];
    const float* fb3 = (const float*)d_in[40];
    const float* Wo  = (const float*)d_in[41];
    const float* bo  = (const float*)d_in[42];
    float* out = (float*)d_out;

    char* b = (char*)d_ws;
    unsigned short* Xh  = (unsigned short*)(b + 0);          // 9,830,400
    unsigned short* Yh  = (unsigned short*)(b + 9830400);    // 9,830,400 (Y1/Y2 fp16, reused)
    unsigned short* HLh = (unsigned short*)(b + 19660800);   // 3,276,800
    unsigned short* Uh  = (unsigned short*)(b + 22937600);   // 6,553,600
    unsigned short* W1h = (unsigned short*)(b + 29491200);   // 1,179,648
    unsigned short* W2h = (unsigned short*)(b + 30670848);   // 327,680
    unsigned short* W3h = (unsigned short*)(b + 30998528);   // 786,432
    float*          AES = (float*)(b + 31784960);            // 64 (+pad)
    float*          LOGV= (float*)(b + 31785216);            // 102,400
    int*            CNT = (int*)(b + 31887616);              // 1,600
    int*            IDX = (int*)(b + 31889216);              // 102,400

    prep_kernel<<<6256, 256, 0, stream>>>(
        wg1, wf1, ws1,
        sWv, dWv, sWq, saq, sWk, sak, dWq, daq, dWk, dak,
        fW1, fW2, fW3, sWe, sae, E1, E2,
        x, wg0, bg0, wf0, bf0, ws0, bs0, ln0g, ln0b, bo,
        W1h, W2h, W3h, AES,
        CNT, IDX, LOGV, Xh, out);

    // G1: Y1 = X @ W1  (M=6400, N=768, K=768) -> fp16, 64x64 tiles, BK=64
    gemm_f16_k64<768, 768, 12, 100><<<dim3(12, 100), 256, 0, stream>>>(Xh, W1h, Yh);

    // epi1: one wave per node
    epi1_kernel<<<1600, 256, 0, stream>>>(Yh, x, bg1, bf1, bs1, ln1g, ln1b, wsk, bsk, HLh);

    // G2: Y2 = HL @ W2 (M=6400, N=576 used, K=256) -> fp16, 128x64 tiles
    gemm_f16_big<256, 640, 9, 50><<<dim3(9, 50), 256, 0, stream>>>(HLh, W2h, Yh);

    // fused attention stages -> U (one block per node, XCD-chunked)
    gat_kernel<<<NODES, 256, 0, stream>>>(Yh, ef, fei, AES, CNT, IDX, LOGV, Uh);

    // G3 + fused tail: out += tanh-fuse(U @ W3) @ Wo
    gemm3_fused<<<dim3(4, 100), 256, 0, stream>>>(Uh, W3h, fb1, fb2, fb3, Wo, out);
}